// Round 2
// baseline (318.512 us; speedup 1.0000x reference)
//
#include <hip/hip_runtime.h>

#define NN 50000
#define EE 800000
#define FIN 256
#define HD 8
#define C1 16
#define HC 128         // HD*C1
#define NC 40
#define NEG 0.2f
#define CAP 64         // ELL capacity per node; P(Poisson(16) >= 64) ~ 1e-17
#define R2 32          // rows per block in k_gemm2
#define BM 64          // k_gemm1 row tile (4 waves x 16 rows)
#define NB_P 98        // ranks per dst partition
#define GB1 (NB_P * 8) // 784 blocks: every partition gets ranks 0..97 (FULL edge coverage)
#define NP_N (NN / 8)  // nodes per partition (6250)

typedef __attribute__((ext_vector_type(8))) short short8;   // 8 bf16 (4 VGPRs)
typedef __attribute__((ext_vector_type(4))) float f32x4;    // MFMA C/D
union FragU { uint4 u; short8 s; };

__device__ __forceinline__ float leaky(float v){ return v > 0.f ? v : NEG * v; }

// fp32 -> bf16 round-to-nearest-even (no NaNs in this workload)
__device__ __forceinline__ unsigned int f2bf(float f){
  unsigned int u = __float_as_uint(f);
  u += 0x7fffu + ((u >> 16) & 1u);
  return u >> 16;
}
__device__ __forceinline__ unsigned int pack2bf(float a, float b){
  return f2bf(a) | (f2bf(b) << 16);
}
__device__ __forceinline__ float bflo(unsigned int u){ return __uint_as_float(u << 16); }
__device__ __forceinline__ float bfhi(unsigned int u){ return __uint_as_float(u & 0xffff0000u); }

// K0: swizzle W1 (fp32 [256][128]) into MFMA B-fragment order:
// frag f = (kt*8+nt)*64+lane holds B[kt*32 + (lane>>4)*8 + j][nt*16 + (lane&15)], j=0..7.
__global__ __launch_bounds__(256) void k_prep(const float* __restrict__ W1,
                                              uint4* __restrict__ W1bfs){
  int f = blockIdx.x * 256 + threadIdx.x;   // 0..4095
  int lane = f & 63, nt = (f >> 6) & 7, kt = f >> 9;
  int quad = lane >> 4, l16 = lane & 15;
  const float* src = W1 + (size_t)(kt * 32 + quad * 8) * HC + nt * 16 + l16;
  unsigned int p[4];
#pragma unroll
  for (int jj = 0; jj < 4; jj++){
    float v0 = src[(size_t)(2 * jj) * HC];
    float v1 = src[(size_t)(2 * jj + 1) * HC];
    p[jj] = pack2bf(v0, v1);
  }
  W1bfs[f] = make_uint4(p[0], p[1], p[2], p[3]);
}

// K1: h1(bf16)[N,128] = x @ W1 via bf16 MFMA 16x16x32. No LDS, no barriers.
// MLP-restructured: all 16 x-loads + kt=0 W1bfs fragments issue BEFORE the edge
// scatter (HBM latency hides under scatter's ei loads + atomics); kt loop runs a
// depth-1 W1bfs prefetch so L2 latency hides under MFMA+pack.
// Fused FIRST: XCD-partitioned ELL scatter. Partition p = blockIdx&7 handles dst in
// [p*6250,(p+1)*6250); rank = blockIdx>>3 in 0..97 for EVERY partition (784 blocks),
// so the strided loop covers all 800k edges exactly once per partition filter.
__global__ __launch_bounds__(256, 3) void k_gemm1(const float* __restrict__ x,
                                                  const uint4* __restrict__ W1bfs,
                                                  const float* __restrict__ att_s,
                                                  const float* __restrict__ att_d,
                                                  const int* __restrict__ ei,
                                                  unsigned short* __restrict__ h1b,
                                                  float* __restrict__ as1,
                                                  float* __restrict__ ad1,
                                                  int* __restrict__ cnt,
                                                  int* __restrict__ srcp){
  const int tid = threadIdx.x;
  const int wave = tid >> 6, lane = tid & 63;
  const int quad = lane >> 4, l16 = lane & 15;
  const int m0 = blockIdx.x * BM + wave * 16;
  int arow = m0 + l16; if (arow >= NN) arow = NN - 1;   // clamp (dup rows benign)
  const float* xr = x + (size_t)arow * FIN;

  // 1) issue ALL x loads (16 x dwordx4 = 64 VGPR) — latency hides under scatter
  float4 xa[16];
#pragma unroll
  for (int kt = 0; kt < 8; kt++){
    xa[2 * kt]     = *(const float4*)(xr + kt * 32 + quad * 8);
    xa[2 * kt + 1] = *(const float4*)(xr + kt * 32 + quad * 8 + 4);
  }
  // 2) prefetch kt=0 B fragments (L2-resident, 32 VGPR)
  FragU bf[8];
#pragma unroll
  for (int nt = 0; nt < 8; nt++) bf[nt].u = W1bfs[nt * 64 + lane];
  __builtin_amdgcn_sched_barrier(0);   // pin the loads above the scatter

  // 3) edge scatter — runs while the loads above are in flight
  const int part = blockIdx.x & 7, rank = blockIdx.x >> 3;
  const int lo = part * NP_N, hi = lo + NP_N;
  for (int e = rank * 256 + tid; e < EE; e += NB_P * 256){
    int d = ei[EE + e];
    if (d >= lo && d < hi){
      int s = ei[e];
      int pos = atomicAdd(&cnt[d], 1);
      if (pos < CAP) srcp[d * CAP + pos] = s;   // clamp guard (never hit per Poisson tail)
    }
  }

  // 4) pack A rows to bf16 fragments (frees xa)
  FragU af[8];
#pragma unroll
  for (int kt = 0; kt < 8; kt++)
    af[kt].u = make_uint4(pack2bf(xa[2 * kt].x,     xa[2 * kt].y),
                          pack2bf(xa[2 * kt].z,     xa[2 * kt].w),
                          pack2bf(xa[2 * kt + 1].x, xa[2 * kt + 1].y),
                          pack2bf(xa[2 * kt + 1].z, xa[2 * kt + 1].w));

  f32x4 acc[8];
#pragma unroll
  for (int t = 0; t < 8; t++) acc[t] = (f32x4){0.f, 0.f, 0.f, 0.f};

  // 5) kt loop with depth-1 B prefetch (fully unrolled; copies rename away)
#pragma unroll
  for (int kt = 0; kt < 8; kt++){
    FragU bn[8];
    if (kt < 7){
#pragma unroll
      for (int nt = 0; nt < 8; nt++)
        bn[nt].u = W1bfs[((kt + 1) * 8 + nt) * 64 + lane];
    }
#pragma unroll
    for (int nt = 0; nt < 8; nt++)
      acc[nt] = __builtin_amdgcn_mfma_f32_16x16x32_bf16(af[kt].s, bf[nt].s, acc[nt], 0, 0, 0);
    if (kt < 7){
#pragma unroll
      for (int nt = 0; nt < 8; nt++) bf[nt] = bn[nt];
    }
  }

  // epilogue: C layout col = lane&15, row = quad*4 + r; head h == nt.
  float sv[8], dv[8];
#pragma unroll
  for (int h = 0; h < 8; h++){ sv[h] = att_s[h * 16 + l16]; dv[h] = att_d[h * 16 + l16]; }
#pragma unroll
  for (int r = 0; r < 4; r++){
    const int gr = m0 + quad * 4 + r;
    float s[8], d[8];
#pragma unroll
    for (int h = 0; h < 8; h++){ s[h] = acc[h][r] * sv[h]; d[h] = acc[h][r] * dv[h]; }
#pragma unroll
    for (int o = 1; o < 16; o <<= 1){
#pragma unroll
      for (int h = 0; h < 8; h++){ s[h] += __shfl_xor(s[h], o); d[h] += __shfl_xor(d[h], o); }
    }
    if (gr < NN){
#pragma unroll
      for (int h = 0; h < 8; h++)
        h1b[(size_t)gr * HC + h * 16 + l16] = (unsigned short)f2bf(acc[h][r]);
      if (l16 == 0){
        *(float4*)(as1 + gr * 8)     = make_float4(s[0], s[1], s[2], s[3]);
        *(float4*)(as1 + gr * 8 + 4) = make_float4(s[4], s[5], s[6], s[7]);
        *(float4*)(ad1 + gr * 8)     = make_float4(d[0], d[1], d[2], d[3]);
        *(float4*)(ad1 + gr * 8 + 4) = make_float4(d[4], d[5], d[6], d[7]);
      }
    }
  }
}

// K2: layer-1 single-pass online-softmax aggregate over ELL lists, bf16 gather,
// 4 edge slots, 2-deep payload pipeline. Self-loop seeded on slot 0.
// 4 independent nodes (waves) per 256-thread block.
__global__ __launch_bounds__(256) void k_agg1(const int* __restrict__ srcp,
                                              const int* __restrict__ cnt,
                                              const float* __restrict__ as1,
                                              const float* __restrict__ ad1,
                                              const unsigned short* __restrict__ h1b,
                                              const float* __restrict__ b1,
                                              unsigned short* __restrict__ h2b){
  const int lane = threadIdx.x & 63;
  const int n = blockIdx.x * 4 + (threadIdx.x >> 6);
  const int q = lane >> 4, t = lane & 15, h = t >> 1;
  const int base = n * CAP;
  int deg = cnt[n]; if (deg > CAP) deg = CAP;
  const float adg = ad1[n * 8 + h];
  float m = -3.0e38f, den = 0.f;
  float acc[8];
#pragma unroll
  for (int c = 0; c < 8; c++) acc[c] = 0.f;

  if (q == 0){   // self loop (weight e^0 = 1 after seeding max)
    const uint4 hv = *(const uint4*)(h1b + (size_t)n * HC + t * 8);
    m = leaky(as1[n * 8 + h] + adg);
    den = 1.f;
    acc[0] = bflo(hv.x); acc[1] = bfhi(hv.x);
    acc[2] = bflo(hv.y); acc[3] = bfhi(hv.y);
    acc[4] = bflo(hv.z); acc[5] = bfhi(hv.z);
    acc[6] = bflo(hv.w); acc[7] = bfhi(hv.w);
  }

  int i = q;
  int sA = (i < deg) ? srcp[base + i] : n;
  uint4 hA = *(const uint4*)(h1b + (size_t)sA * HC + t * 8);
  float aA = as1[sA * 8 + h];
  int sB = (i + 4 < deg) ? srcp[base + i + 4] : n;
  while (i < deg){
    const uint4 hB = *(const uint4*)(h1b + (size_t)sB * HC + t * 8);   // next payload in flight
    const float aB = as1[sB * 8 + h];
    const int sC = (i + 8 < deg) ? srcp[base + i + 8] : n;             // index 2 ahead
    float v = leaky(aA + adg);
    float mn = fmaxf(m, v);
    float r = __expf(m - mn), w = __expf(v - mn);
    den = den * r + w;
    acc[0] = acc[0] * r + w * bflo(hA.x); acc[1] = acc[1] * r + w * bfhi(hA.x);
    acc[2] = acc[2] * r + w * bflo(hA.y); acc[3] = acc[3] * r + w * bfhi(hA.y);
    acc[4] = acc[4] * r + w * bflo(hA.z); acc[5] = acc[5] * r + w * bfhi(hA.z);
    acc[6] = acc[6] * r + w * bflo(hA.w); acc[7] = acc[7] * r + w * bfhi(hA.w);
    m = mn;
    hA = hB; aA = aB; sA = sB; sB = sC;
    i += 4;
  }
  // combine 4 edge slots
#pragma unroll
  for (int o = 16; o <= 32; o <<= 1){
    float mo = __shfl_xor(m, o);
    float dno = __shfl_xor(den, o);
    float mn = fmaxf(m, mo);
    float ra = __expf(m - mn), rb = __expf(mo - mn);
    den = den * ra + dno * rb;
#pragma unroll
    for (int c = 0; c < 8; c++){
      float ao = __shfl_xor(acc[c], o);
      acc[c] = acc[c] * ra + ao * rb;
    }
    m = mn;
  }
  if (q == 0){
    float invd = 1.f / (den + 1e-16f);
    float o8[8];
    const float4 bA = *(const float4*)(b1 + t * 8);
    const float4 bB = *(const float4*)(b1 + t * 8 + 4);
    o8[0] = acc[0] * invd + bA.x; o8[1] = acc[1] * invd + bA.y;
    o8[2] = acc[2] * invd + bA.z; o8[3] = acc[3] * invd + bA.w;
    o8[4] = acc[4] * invd + bB.x; o8[5] = acc[5] * invd + bB.y;
    o8[6] = acc[6] * invd + bB.z; o8[7] = acc[7] * invd + bB.w;
#pragma unroll
    for (int c = 0; c < 8; c++) o8[c] = (o8[c] > 0.f) ? o8[c] : (__expf(o8[c]) - 1.f);
    uint4 pk;
    pk.x = pack2bf(o8[0], o8[1]); pk.y = pack2bf(o8[2], o8[3]);
    pk.z = pack2bf(o8[4], o8[5]); pk.w = pack2bf(o8[6], o8[7]);
    *(uint4*)(h2b + (size_t)n * HC + t * 8) = pk;
  }
}

// K3: g(bf16)[N,40] = h2(bf16) @ W2; fused att2 dots.
__global__ __launch_bounds__(256) void k_gemm2(const unsigned short* __restrict__ h2b,
                                               const float* __restrict__ W2,
                                               const float* __restrict__ att_s2,
                                               const float* __restrict__ att_d2,
                                               unsigned short* __restrict__ gb,
                                               float* __restrict__ as2,
                                               float* __restrict__ ad2){
  __shared__ float hs[R2][HC + 2];
  __shared__ float w2s[HC * NC];
  const int tid = threadIdx.x;
  const int r0 = blockIdx.x * R2;
  for (int i = tid; i < HC * NC; i += 256) w2s[i] = W2[i];
  for (int i = tid; i < R2 * (HC / 2); i += 256){      // unpack bf16 pairs
    int r = i / (HC / 2), c = i % (HC / 2);
    unsigned int u = (r0 + r < NN) ? ((const unsigned int*)h2b)[(size_t)(r0 + r) * (HC / 2) + c] : 0u;
    hs[r][2 * c]     = bflo(u);
    hs[r][2 * c + 1] = bfhi(u);
  }
  __syncthreads();
  const int r = tid >> 3, j = tid & 7;
  float acc[5] = {0.f, 0.f, 0.f, 0.f, 0.f};
  for (int k = 0; k < HC; k++){
    float hv = hs[r][k];
#pragma unroll
    for (int q = 0; q < 5; q++) acc[q] += hv * w2s[k * NC + j + 8 * q];
  }
  const int node = r0 + r;
  if (node < NN){
    float s = 0.f, d = 0.f;
#pragma unroll
    for (int q = 0; q < 5; q++){
      int c = j + 8 * q;
      gb[(size_t)node * NC + c] = (unsigned short)f2bf(acc[q]);
      s += acc[q] * att_s2[c];
      d += acc[q] * att_d2[c];
    }
#pragma unroll
    for (int o = 1; o < 8; o <<= 1){ s += __shfl_xor(s, o); d += __shfl_xor(d, o); }
    if (j == 0){ as2[node] = s; ad2[node] = d; }
  }
}

// K4: layer-2 single-pass aggregate over ELL (bf16 gather) + bias + log_softmax.
// One wave per node, 4 nodes per 256-thread block; self-loop seeded on half 0.
__global__ __launch_bounds__(256) void k_agg2(const int* __restrict__ srcp,
                                              const int* __restrict__ cnt,
                                              const float* __restrict__ as2,
                                              const float* __restrict__ ad2,
                                              const unsigned short* __restrict__ gb,
                                              const float* __restrict__ b2,
                                              float* __restrict__ out){
  const int lane = threadIdx.x & 63, w = threadIdx.x >> 6;
  const int n = blockIdx.x * 4 + w;
  const int half = lane >> 5, c2 = lane & 31;
  const int base = n * CAP;
  int deg = cnt[n]; if (deg > CAP) deg = CAP;
  const float ad = ad2[n];
  const bool act = (c2 < 20);
  float m = -3.0e38f, den = 0.f, ax = 0.f, ay = 0.f;
  if (half == 0){   // self loop
    m = leaky(as2[n] + ad);
    den = 1.f;
    if (act){
      unsigned int u = *(const unsigned int*)(gb + (size_t)n * NC + c2 * 2);
      ax = bflo(u); ay = bfhi(u);
    }
  }
  int i = half;
  int sA = (i < deg) ? srcp[base + i] : n;
  while (i < deg){
    int sB = (i + 2 < deg) ? srcp[base + i + 2] : n;
    float v = leaky(as2[sA] + ad);
    float gx = 0.f, gy = 0.f;
    if (act){
      unsigned int u = *(const unsigned int*)(gb + (size_t)sA * NC + c2 * 2);
      gx = bflo(u); gy = bfhi(u);
    }
    float mn = fmaxf(m, v);
    float r = __expf(m - mn), wgt = __expf(v - mn);
    den = den * r + wgt;
    ax = ax * r + wgt * gx; ay = ay * r + wgt * gy;
    m = mn;
    sA = sB; i += 2;
  }
  float mo = __shfl_xor(m, 32), dno = __shfl_xor(den, 32);
  float bx = __shfl_xor(ax, 32), by = __shfl_xor(ay, 32);
  float mn = fmaxf(m, mo);
  float ra = __expf(m - mn), rb = __expf(mo - mn);
  den = den * ra + dno * rb;
  ax = ax * ra + bx * rb; ay = ay * ra + by * rb;
  __shared__ float fin[4][NC];
  if (half == 0 && act){
    float invd = 1.f / (den + 1e-16f);
    float f0 = ax * invd + b2[c2 * 2];
    float f1 = ay * invd + b2[c2 * 2 + 1];
    out[(size_t)n * NC + c2 * 2]     = f0;
    out[(size_t)n * NC + c2 * 2 + 1] = f1;
    fin[w][c2 * 2] = f0; fin[w][c2 * 2 + 1] = f1;
  }
  __syncthreads();
  float v = (lane < NC) ? fin[w][lane] : -3.4e38f;
  float mx = v;
#pragma unroll
  for (int o = 32; o; o >>= 1) mx = fmaxf(mx, __shfl_xor(mx, o));
  float ex = (lane < NC) ? __expf(v - mx) : 0.f;
#pragma unroll
  for (int o = 32; o; o >>= 1) ex += __shfl_xor(ex, o);
  float lse = mx + __logf(ex);
  if (lane < NC) out[(size_t)(NN * NC) + (size_t)n * NC + lane] = v - lse;
}

extern "C" void kernel_launch(void* const* d_in, const int* in_sizes, int n_in,
                              void* d_out, int out_size, void* d_ws, size_t ws_size,
                              hipStream_t stream){
  const float* x      = (const float*)d_in[0];
  const int*   ei     = (const int*)  d_in[1];
  const float* W1     = (const float*)d_in[3];
  const float* att_s1 = (const float*)d_in[4];
  const float* att_d1 = (const float*)d_in[5];
  const float* b1     = (const float*)d_in[6];
  const float* W2     = (const float*)d_in[7];
  const float* att_s2 = (const float*)d_in[8];
  const float* att_d2 = (const float*)d_in[9];
  const float* b2     = (const float*)d_in[10];
  float* out = (float*)d_out;

  char* wp = (char*)d_ws;
  uint4* W1bfs = (uint4*)wp;                 wp += (size_t)4096 * 16;      // 64 KB
  unsigned short* h1b = (unsigned short*)wp; wp += (size_t)NN * HC * 2;    // 12.8 MB
  unsigned short* h2b = (unsigned short*)wp; wp += (size_t)NN * HC * 2;    // 12.8 MB
  unsigned short* gb  = (unsigned short*)wp; wp += (size_t)NN * NC * 2;    // 4 MB
  float* as1 = (float*)wp;                   wp += (size_t)NN * HD * 4;
  float* ad1 = (float*)wp;                   wp += (size_t)NN * HD * 4;
  float* as2 = (float*)wp;                   wp += (size_t)NN * 4;
  float* ad2 = (float*)wp;                   wp += (size_t)NN * 4;
  int* cnt   = (int*)wp;                     wp += (size_t)NN * 4;
  int* srcp  = (int*)wp;                     wp += (size_t)NN * CAP * 4;   // 12.8 MB

  hipMemsetAsync(cnt, 0, (size_t)NN * sizeof(int), stream);
  k_prep  <<<16, 256, 0, stream>>>(W1, W1bfs);
  k_gemm1 <<<GB1, 256, 0, stream>>>(x, W1bfs, att_s1, att_d1, ei, h1b, as1, ad1, cnt, srcp);
  k_agg1  <<<NN / 4, 256, 0, stream>>>(srcp, cnt, as1, ad1, h1b, b1, h2b);
  k_gemm2 <<<(NN + R2 - 1) / R2, 256, 0, stream>>>(h2b, W2, att_s2, att_d2, gb, as2, ad2);
  k_agg2  <<<NN / 4, 256, 0, stream>>>(srcp, cnt, as2, ad2, gb, b2, out);
}

// Round 3
// 294.940 us; speedup vs baseline: 1.0799x; 1.0799x over previous
//
#include <hip/hip_runtime.h>

#define NN 50000
#define EE 800000
#define FIN 256
#define HD 8
#define C1 16
#define HC 128         // HD*C1
#define NC 40
#define NEG 0.2f
#define CAP 64         // ELL capacity per node; P(Poisson(16) >= 64) ~ 1e-17
#define R2 32          // rows per block in k_gemm2
#define BM 64          // k_gemm1 row tile (4 waves x 16 rows)
#define GB1 ((NN + BM - 1) / BM)  // 782 pure-GEMM blocks
#define NP_N (NN / 8)  // nodes per partition (6250)
#define SCB 2048       // scatter blocks (8 partitions x 256 ranks)

typedef __attribute__((ext_vector_type(8))) short short8;   // 8 bf16 (4 VGPRs)
typedef __attribute__((ext_vector_type(4))) float f32x4;    // MFMA C/D
union FragU { uint4 u; short8 s; };

__device__ __forceinline__ float leaky(float v){ return v > 0.f ? v : NEG * v; }

// fp32 -> bf16 round-to-nearest-even (no NaNs in this workload)
__device__ __forceinline__ unsigned int f2bf(float f){
  unsigned int u = __float_as_uint(f);
  u += 0x7fffu + ((u >> 16) & 1u);
  return u >> 16;
}
__device__ __forceinline__ unsigned int pack2bf(float a, float b){
  return f2bf(a) | (f2bf(b) << 16);
}
__device__ __forceinline__ float bflo(unsigned int u){ return __uint_as_float(u << 16); }
__device__ __forceinline__ float bfhi(unsigned int u){ return __uint_as_float(u & 0xffff0000u); }

// K0: blocks 0..15 swizzle W1 into MFMA B-fragment order; blocks 16..2063 run the
// XCD-partitioned ELL scatter at HIGH occupancy (tiny VGPR state -> up to 32 waves/CU,
// vs 12/CU when this was fused into the GEMM). Partition p = b&7 matches the XCD the
// block lands on (round-robin dispatch), so cnt/srcp atomics stay XCD-L2-local.
__global__ __launch_bounds__(256) void k_prep(const float* __restrict__ W1,
                                              uint4* __restrict__ W1bfs,
                                              const int* __restrict__ ei,
                                              int* __restrict__ cnt,
                                              int* __restrict__ srcp){
  const int tid = threadIdx.x;
  if (blockIdx.x < 16){
    int f = blockIdx.x * 256 + tid;   // 0..4095
    int lane = f & 63, nt = (f >> 6) & 7, kt = f >> 9;
    int quad = lane >> 4, l16 = lane & 15;
    const float* src = W1 + (size_t)(kt * 32 + quad * 8) * HC + nt * 16 + l16;
    unsigned int p[4];
#pragma unroll
    for (int jj = 0; jj < 4; jj++){
      float v0 = src[(size_t)(2 * jj) * HC];
      float v1 = src[(size_t)(2 * jj + 1) * HC];
      p[jj] = pack2bf(v0, v1);
    }
    W1bfs[f] = make_uint4(p[0], p[1], p[2], p[3]);
    return;
  }
  const int b = blockIdx.x - 16;          // 0..2047 (16%8==0 keeps b&7 == XCD id)
  const int part = b & 7, rank = b >> 3;  // rank 0..255
  const int lo = part * NP_N, hi = lo + NP_N;
  for (int e = rank * 256 + tid; e < EE; e += 256 * 256){
    int d = ei[EE + e];
    if (d >= lo && d < hi){
      int s = ei[e];
      int pos = atomicAdd(&cnt[d], 1);
      if (pos < CAP) srcp[d * CAP + pos] = s;   // clamp guard (never hit per Poisson tail)
    }
  }
}

// K1: PURE GEMM h1(bf16)[N,128] = x @ W1 via bf16 MFMA 16x16x32. No LDS, no barriers,
// no scatter — single straight-line body so the scheduler can keep all 16 x-loads
// (HBM) and the depth-1 W1bfs prefetch (L2) in flight. launch_bounds(256,3) raises
// the register-pressure target to ~168 VGPR (3 waves/SIMD = all 12 waves/CU we have).
__global__ __launch_bounds__(256, 3) void k_gemm1(const float* __restrict__ x,
                                                  const uint4* __restrict__ W1bfs,
                                                  const float* __restrict__ att_s,
                                                  const float* __restrict__ att_d,
                                                  unsigned short* __restrict__ h1b,
                                                  float* __restrict__ as1,
                                                  float* __restrict__ ad1){
  const int tid = threadIdx.x;
  const int wave = tid >> 6, lane = tid & 63;
  const int quad = lane >> 4, l16 = lane & 15;
  const int m0 = blockIdx.x * BM + wave * 16;
  int arow = m0 + l16; if (arow >= NN) arow = NN - 1;   // clamp (dup rows benign)
  const float* xr = x + (size_t)arow * FIN;

  // issue ALL x loads (16 x dwordx4) — HBM latency overlaps across all 16
  float4 xa[16];
#pragma unroll
  for (int kt = 0; kt < 8; kt++){
    xa[2 * kt]     = *(const float4*)(xr + kt * 32 + quad * 8);
    xa[2 * kt + 1] = *(const float4*)(xr + kt * 32 + quad * 8 + 4);
  }
  // kt=0 B fragments (L2-resident)
  FragU bf[8];
#pragma unroll
  for (int nt = 0; nt < 8; nt++) bf[nt].u = W1bfs[nt * 64 + lane];

  f32x4 acc[8];
#pragma unroll
  for (int t = 0; t < 8; t++) acc[t] = (f32x4){0.f, 0.f, 0.f, 0.f};

  // kt loop: depth-1 B prefetch; A packed per-kt (vmcnt staggers naturally)
#pragma unroll
  for (int kt = 0; kt < 8; kt++){
    FragU bn[8];
    if (kt < 7){
#pragma unroll
      for (int nt = 0; nt < 8; nt++)
        bn[nt].u = W1bfs[((kt + 1) * 8 + nt) * 64 + lane];
    }
    FragU af;
    af.u = make_uint4(pack2bf(xa[2 * kt].x,     xa[2 * kt].y),
                      pack2bf(xa[2 * kt].z,     xa[2 * kt].w),
                      pack2bf(xa[2 * kt + 1].x, xa[2 * kt + 1].y),
                      pack2bf(xa[2 * kt + 1].z, xa[2 * kt + 1].w));
#pragma unroll
    for (int nt = 0; nt < 8; nt++)
      acc[nt] = __builtin_amdgcn_mfma_f32_16x16x32_bf16(af.s, bf[nt].s, acc[nt], 0, 0, 0);
    if (kt < 7){
#pragma unroll
      for (int nt = 0; nt < 8; nt++) bf[nt] = bn[nt];
    }
  }

  // epilogue: C layout col = lane&15, row = quad*4 + r; head h == nt.
  float sv[8], dv[8];
#pragma unroll
  for (int h = 0; h < 8; h++){ sv[h] = att_s[h * 16 + l16]; dv[h] = att_d[h * 16 + l16]; }
#pragma unroll
  for (int r = 0; r < 4; r++){
    const int gr = m0 + quad * 4 + r;
    float s[8], d[8];
#pragma unroll
    for (int h = 0; h < 8; h++){ s[h] = acc[h][r] * sv[h]; d[h] = acc[h][r] * dv[h]; }
#pragma unroll
    for (int o = 1; o < 16; o <<= 1){
#pragma unroll
      for (int h = 0; h < 8; h++){ s[h] += __shfl_xor(s[h], o); d[h] += __shfl_xor(d[h], o); }
    }
    if (gr < NN){
#pragma unroll
      for (int h = 0; h < 8; h++)
        h1b[(size_t)gr * HC + h * 16 + l16] = (unsigned short)f2bf(acc[h][r]);
      if (l16 == 0){
        *(float4*)(as1 + gr * 8)     = make_float4(s[0], s[1], s[2], s[3]);
        *(float4*)(as1 + gr * 8 + 4) = make_float4(s[4], s[5], s[6], s[7]);
        *(float4*)(ad1 + gr * 8)     = make_float4(d[0], d[1], d[2], d[3]);
        *(float4*)(ad1 + gr * 8 + 4) = make_float4(d[4], d[5], d[6], d[7]);
      }
    }
  }
}

// K2: layer-1 single-pass online-softmax aggregate over ELL lists, bf16 gather,
// 4 edge slots, 2-deep payload pipeline. Self-loop seeded on slot 0.
// 4 independent nodes (waves) per 256-thread block.
__global__ __launch_bounds__(256) void k_agg1(const int* __restrict__ srcp,
                                              const int* __restrict__ cnt,
                                              const float* __restrict__ as1,
                                              const float* __restrict__ ad1,
                                              const unsigned short* __restrict__ h1b,
                                              const float* __restrict__ b1,
                                              unsigned short* __restrict__ h2b){
  const int lane = threadIdx.x & 63;
  const int n = blockIdx.x * 4 + (threadIdx.x >> 6);
  const int q = lane >> 4, t = lane & 15, h = t >> 1;
  const int base = n * CAP;
  int deg = cnt[n]; if (deg > CAP) deg = CAP;
  const float adg = ad1[n * 8 + h];
  float m = -3.0e38f, den = 0.f;
  float acc[8];
#pragma unroll
  for (int c = 0; c < 8; c++) acc[c] = 0.f;

  if (q == 0){   // self loop (weight e^0 = 1 after seeding max)
    const uint4 hv = *(const uint4*)(h1b + (size_t)n * HC + t * 8);
    m = leaky(as1[n * 8 + h] + adg);
    den = 1.f;
    acc[0] = bflo(hv.x); acc[1] = bfhi(hv.x);
    acc[2] = bflo(hv.y); acc[3] = bfhi(hv.y);
    acc[4] = bflo(hv.z); acc[5] = bfhi(hv.z);
    acc[6] = bflo(hv.w); acc[7] = bfhi(hv.w);
  }

  int i = q;
  int sA = (i < deg) ? srcp[base + i] : n;
  uint4 hA = *(const uint4*)(h1b + (size_t)sA * HC + t * 8);
  float aA = as1[sA * 8 + h];
  int sB = (i + 4 < deg) ? srcp[base + i + 4] : n;
  while (i < deg){
    const uint4 hB = *(const uint4*)(h1b + (size_t)sB * HC + t * 8);   // next payload in flight
    const float aB = as1[sB * 8 + h];
    const int sC = (i + 8 < deg) ? srcp[base + i + 8] : n;             // index 2 ahead
    float v = leaky(aA + adg);
    float mn = fmaxf(m, v);
    float r = __expf(m - mn), w = __expf(v - mn);
    den = den * r + w;
    acc[0] = acc[0] * r + w * bflo(hA.x); acc[1] = acc[1] * r + w * bfhi(hA.x);
    acc[2] = acc[2] * r + w * bflo(hA.y); acc[3] = acc[3] * r + w * bfhi(hA.y);
    acc[4] = acc[4] * r + w * bflo(hA.z); acc[5] = acc[5] * r + w * bfhi(hA.z);
    acc[6] = acc[6] * r + w * bflo(hA.w); acc[7] = acc[7] * r + w * bfhi(hA.w);
    m = mn;
    hA = hB; aA = aB; sA = sB; sB = sC;
    i += 4;
  }
  // combine 4 edge slots
#pragma unroll
  for (int o = 16; o <= 32; o <<= 1){
    float mo = __shfl_xor(m, o);
    float dno = __shfl_xor(den, o);
    float mn = fmaxf(m, mo);
    float ra = __expf(m - mn), rb = __expf(mo - mn);
    den = den * ra + dno * rb;
#pragma unroll
    for (int c = 0; c < 8; c++){
      float ao = __shfl_xor(acc[c], o);
      acc[c] = acc[c] * ra + ao * rb;
    }
    m = mn;
  }
  if (q == 0){
    float invd = 1.f / (den + 1e-16f);
    float o8[8];
    const float4 bA = *(const float4*)(b1 + t * 8);
    const float4 bB = *(const float4*)(b1 + t * 8 + 4);
    o8[0] = acc[0] * invd + bA.x; o8[1] = acc[1] * invd + bA.y;
    o8[2] = acc[2] * invd + bA.z; o8[3] = acc[3] * invd + bA.w;
    o8[4] = acc[4] * invd + bB.x; o8[5] = acc[5] * invd + bB.y;
    o8[6] = acc[6] * invd + bB.z; o8[7] = acc[7] * invd + bB.w;
#pragma unroll
    for (int c = 0; c < 8; c++) o8[c] = (o8[c] > 0.f) ? o8[c] : (__expf(o8[c]) - 1.f);
    uint4 pk;
    pk.x = pack2bf(o8[0], o8[1]); pk.y = pack2bf(o8[2], o8[3]);
    pk.z = pack2bf(o8[4], o8[5]); pk.w = pack2bf(o8[6], o8[7]);
    *(uint4*)(h2b + (size_t)n * HC + t * 8) = pk;
  }
}

// K3: g(bf16)[N,40] = h2(bf16) @ W2; fused att2 dots.
__global__ __launch_bounds__(256) void k_gemm2(const unsigned short* __restrict__ h2b,
                                               const float* __restrict__ W2,
                                               const float* __restrict__ att_s2,
                                               const float* __restrict__ att_d2,
                                               unsigned short* __restrict__ gb,
                                               float* __restrict__ as2,
                                               float* __restrict__ ad2){
  __shared__ float hs[R2][HC + 2];
  __shared__ float w2s[HC * NC];
  const int tid = threadIdx.x;
  const int r0 = blockIdx.x * R2;
  for (int i = tid; i < HC * NC; i += 256) w2s[i] = W2[i];
  for (int i = tid; i < R2 * (HC / 2); i += 256){      // unpack bf16 pairs
    int r = i / (HC / 2), c = i % (HC / 2);
    unsigned int u = (r0 + r < NN) ? ((const unsigned int*)h2b)[(size_t)(r0 + r) * (HC / 2) + c] : 0u;
    hs[r][2 * c]     = bflo(u);
    hs[r][2 * c + 1] = bfhi(u);
  }
  __syncthreads();
  const int r = tid >> 3, j = tid & 7;
  float acc[5] = {0.f, 0.f, 0.f, 0.f, 0.f};
  for (int k = 0; k < HC; k++){
    float hv = hs[r][k];
#pragma unroll
    for (int q = 0; q < 5; q++) acc[q] += hv * w2s[k * NC + j + 8 * q];
  }
  const int node = r0 + r;
  if (node < NN){
    float s = 0.f, d = 0.f;
#pragma unroll
    for (int q = 0; q < 5; q++){
      int c = j + 8 * q;
      gb[(size_t)node * NC + c] = (unsigned short)f2bf(acc[q]);
      s += acc[q] * att_s2[c];
      d += acc[q] * att_d2[c];
    }
#pragma unroll
    for (int o = 1; o < 8; o <<= 1){ s += __shfl_xor(s, o); d += __shfl_xor(d, o); }
    if (j == 0){ as2[node] = s; ad2[node] = d; }
  }
}

// K4: layer-2 single-pass aggregate over ELL (bf16 gather) + bias + log_softmax.
// One wave per node, 4 nodes per 256-thread block; self-loop seeded on half 0.
__global__ __launch_bounds__(256) void k_agg2(const int* __restrict__ srcp,
                                              const int* __restrict__ cnt,
                                              const float* __restrict__ as2,
                                              const float* __restrict__ ad2,
                                              const unsigned short* __restrict__ gb,
                                              const float* __restrict__ b2,
                                              float* __restrict__ out){
  const int lane = threadIdx.x & 63, w = threadIdx.x >> 6;
  const int n = blockIdx.x * 4 + w;
  const int half = lane >> 5, c2 = lane & 31;
  const int base = n * CAP;
  int deg = cnt[n]; if (deg > CAP) deg = CAP;
  const float ad = ad2[n];
  const bool act = (c2 < 20);
  float m = -3.0e38f, den = 0.f, ax = 0.f, ay = 0.f;
  if (half == 0){   // self loop
    m = leaky(as2[n] + ad);
    den = 1.f;
    if (act){
      unsigned int u = *(const unsigned int*)(gb + (size_t)n * NC + c2 * 2);
      ax = bflo(u); ay = bfhi(u);
    }
  }
  int i = half;
  int sA = (i < deg) ? srcp[base + i] : n;
  while (i < deg){
    int sB = (i + 2 < deg) ? srcp[base + i + 2] : n;
    float v = leaky(as2[sA] + ad);
    float gx = 0.f, gy = 0.f;
    if (act){
      unsigned int u = *(const unsigned int*)(gb + (size_t)sA * NC + c2 * 2);
      gx = bflo(u); gy = bfhi(u);
    }
    float mn = fmaxf(m, v);
    float r = __expf(m - mn), wgt = __expf(v - mn);
    den = den * r + wgt;
    ax = ax * r + wgt * gx; ay = ay * r + wgt * gy;
    m = mn;
    sA = sB; i += 2;
  }
  float mo = __shfl_xor(m, 32), dno = __shfl_xor(den, 32);
  float bx = __shfl_xor(ax, 32), by = __shfl_xor(ay, 32);
  float mn = fmaxf(m, mo);
  float ra = __expf(m - mn), rb = __expf(mo - mn);
  den = den * ra + dno * rb;
  ax = ax * ra + bx * rb; ay = ay * ra + by * rb;
  __shared__ float fin[4][NC];
  if (half == 0 && act){
    float invd = 1.f / (den + 1e-16f);
    float f0 = ax * invd + b2[c2 * 2];
    float f1 = ay * invd + b2[c2 * 2 + 1];
    out[(size_t)n * NC + c2 * 2]     = f0;
    out[(size_t)n * NC + c2 * 2 + 1] = f1;
    fin[w][c2 * 2] = f0; fin[w][c2 * 2 + 1] = f1;
  }
  __syncthreads();
  float v = (lane < NC) ? fin[w][lane] : -3.4e38f;
  float mx = v;
#pragma unroll
  for (int o = 32; o; o >>= 1) mx = fmaxf(mx, __shfl_xor(mx, o));
  float ex = (lane < NC) ? __expf(v - mx) : 0.f;
#pragma unroll
  for (int o = 32; o; o >>= 1) ex += __shfl_xor(ex, o);
  float lse = mx + __logf(ex);
  if (lane < NC) out[(size_t)(NN * NC) + (size_t)n * NC + lane] = v - lse;
}

extern "C" void kernel_launch(void* const* d_in, const int* in_sizes, int n_in,
                              void* d_out, int out_size, void* d_ws, size_t ws_size,
                              hipStream_t stream){
  const float* x      = (const float*)d_in[0];
  const int*   ei     = (const int*)  d_in[1];
  const float* W1     = (const float*)d_in[3];
  const float* att_s1 = (const float*)d_in[4];
  const float* att_d1 = (const float*)d_in[5];
  const float* b1     = (const float*)d_in[6];
  const float* W2     = (const float*)d_in[7];
  const float* att_s2 = (const float*)d_in[8];
  const float* att_d2 = (const float*)d_in[9];
  const float* b2     = (const float*)d_in[10];
  float* out = (float*)d_out;

  char* wp = (char*)d_ws;
  uint4* W1bfs = (uint4*)wp;                 wp += (size_t)4096 * 16;      // 64 KB
  unsigned short* h1b = (unsigned short*)wp; wp += (size_t)NN * HC * 2;    // 12.8 MB
  unsigned short* h2b = (unsigned short*)wp; wp += (size_t)NN * HC * 2;    // 12.8 MB
  unsigned short* gb  = (unsigned short*)wp; wp += (size_t)NN * NC * 2;    // 4 MB
  float* as1 = (float*)wp;                   wp += (size_t)NN * HD * 4;
  float* ad1 = (float*)wp;                   wp += (size_t)NN * HD * 4;
  float* as2 = (float*)wp;                   wp += (size_t)NN * 4;
  float* ad2 = (float*)wp;                   wp += (size_t)NN * 4;
  int* cnt   = (int*)wp;                     wp += (size_t)NN * 4;
  int* srcp  = (int*)wp;                     wp += (size_t)NN * CAP * 4;   // 12.8 MB

  hipMemsetAsync(cnt, 0, (size_t)NN * sizeof(int), stream);
  k_prep  <<<16 + SCB, 256, 0, stream>>>(W1, W1bfs, ei, cnt, srcp);
  k_gemm1 <<<GB1, 256, 0, stream>>>(x, W1bfs, att_s1, att_d1, h1b, as1, ad1);
  k_agg1  <<<NN / 4, 256, 0, stream>>>(srcp, cnt, as1, ad1, h1b, b1, h2b);
  k_gemm2 <<<(NN + R2 - 1) / R2, 256, 0, stream>>>(h2b, W2, att_s2, att_d2, gb, as2, ad2);
  k_agg2  <<<NN / 4, 256, 0, stream>>>(srcp, cnt, as2, ad2, gb, b2, out);
}

// Round 4
// 291.377 us; speedup vs baseline: 1.0931x; 1.0122x over previous
//
#include <hip/hip_runtime.h>

#define NN 50000
#define EE 800000
#define FIN 256
#define HD 8
#define C1 16
#define HC 128         // HD*C1
#define NC 40
#define NEG 0.2f
#define CAP 64         // ELL capacity per node; P(Poisson(16) >= 64) ~ 1e-17
#define R2 32          // rows per block in k_gemm2
#define BM 64          // k_gemm1 row tile (4 waves x 16 rows)
#define GB1 ((NN + BM - 1) / BM)  // 782 pure-GEMM blocks
#define NP_N (NN / 8)  // nodes per partition (6250)
#define SCB 2048       // scatter blocks (8 partitions x 256 ranks)

typedef __attribute__((ext_vector_type(8))) short short8;   // 8 bf16 (4 VGPRs)
typedef __attribute__((ext_vector_type(4))) float f32x4;    // MFMA C/D
union FragU { uint4 u; short8 s; };

__device__ __forceinline__ float leaky(float v){ return v > 0.f ? v : NEG * v; }

// fp32 -> bf16 round-to-nearest-even (no NaNs in this workload)
__device__ __forceinline__ unsigned int f2bf(float f){
  unsigned int u = __float_as_uint(f);
  u += 0x7fffu + ((u >> 16) & 1u);
  return u >> 16;
}
__device__ __forceinline__ unsigned int pack2bf(float a, float b){
  return f2bf(a) | (f2bf(b) << 16);
}
__device__ __forceinline__ float bflo(unsigned int u){ return __uint_as_float(u << 16); }
__device__ __forceinline__ float bfhi(unsigned int u){ return __uint_as_float(u & 0xffff0000u); }
__device__ __forceinline__ float bfus(unsigned short u){ return __uint_as_float((unsigned int)u << 16); }

// K0: blocks 0..15 swizzle W1 into MFMA B-fragment order; blocks 16..2063 run the
// XCD-partitioned ELL scatter at HIGH occupancy. Partition p = b&7 matches the XCD
// the block lands on (round-robin dispatch), so cnt/srcp atomics stay XCD-L2-local.
__global__ __launch_bounds__(256) void k_prep(const float* __restrict__ W1,
                                              uint4* __restrict__ W1bfs,
                                              const int* __restrict__ ei,
                                              int* __restrict__ cnt,
                                              int* __restrict__ srcp){
  const int tid = threadIdx.x;
  if (blockIdx.x < 16){
    int f = blockIdx.x * 256 + tid;   // 0..4095
    int lane = f & 63, nt = (f >> 6) & 7, kt = f >> 9;
    int quad = lane >> 4, l16 = lane & 15;
    const float* src = W1 + (size_t)(kt * 32 + quad * 8) * HC + nt * 16 + l16;
    unsigned int p[4];
#pragma unroll
    for (int jj = 0; jj < 4; jj++){
      float v0 = src[(size_t)(2 * jj) * HC];
      float v1 = src[(size_t)(2 * jj + 1) * HC];
      p[jj] = pack2bf(v0, v1);
    }
    W1bfs[f] = make_uint4(p[0], p[1], p[2], p[3]);
    return;
  }
  const int b = blockIdx.x - 16;          // 0..2047 (16%8==0 keeps b&7 == XCD id)
  const int part = b & 7, rank = b >> 3;  // rank 0..255
  const int lo = part * NP_N, hi = lo + NP_N;
  for (int e = rank * 256 + tid; e < EE; e += 256 * 256){
    int d = ei[EE + e];
    if (d >= lo && d < hi){
      int s = ei[e];
      int pos = atomicAdd(&cnt[d], 1);
      if (pos < CAP) srcp[d * CAP + pos] = s;   // clamp guard (never hit per Poisson tail)
    }
  }
}

// K1: PURE GEMM h1(bf16)[N,128] = x @ W1 via bf16 MFMA 16x16x32. No LDS, no barriers.
__global__ __launch_bounds__(256, 3) void k_gemm1(const float* __restrict__ x,
                                                  const uint4* __restrict__ W1bfs,
                                                  const float* __restrict__ att_s,
                                                  const float* __restrict__ att_d,
                                                  unsigned short* __restrict__ h1b,
                                                  float* __restrict__ as1,
                                                  float* __restrict__ ad1){
  const int tid = threadIdx.x;
  const int wave = tid >> 6, lane = tid & 63;
  const int quad = lane >> 4, l16 = lane & 15;
  const int m0 = blockIdx.x * BM + wave * 16;
  int arow = m0 + l16; if (arow >= NN) arow = NN - 1;   // clamp (dup rows benign)
  const float* xr = x + (size_t)arow * FIN;

  float4 xa[16];
#pragma unroll
  for (int kt = 0; kt < 8; kt++){
    xa[2 * kt]     = *(const float4*)(xr + kt * 32 + quad * 8);
    xa[2 * kt + 1] = *(const float4*)(xr + kt * 32 + quad * 8 + 4);
  }
  FragU bf[8];
#pragma unroll
  for (int nt = 0; nt < 8; nt++) bf[nt].u = W1bfs[nt * 64 + lane];

  f32x4 acc[8];
#pragma unroll
  for (int t = 0; t < 8; t++) acc[t] = (f32x4){0.f, 0.f, 0.f, 0.f};

#pragma unroll
  for (int kt = 0; kt < 8; kt++){
    FragU bn[8];
    if (kt < 7){
#pragma unroll
      for (int nt = 0; nt < 8; nt++)
        bn[nt].u = W1bfs[((kt + 1) * 8 + nt) * 64 + lane];
    }
    FragU af;
    af.u = make_uint4(pack2bf(xa[2 * kt].x,     xa[2 * kt].y),
                      pack2bf(xa[2 * kt].z,     xa[2 * kt].w),
                      pack2bf(xa[2 * kt + 1].x, xa[2 * kt + 1].y),
                      pack2bf(xa[2 * kt + 1].z, xa[2 * kt + 1].w));
#pragma unroll
    for (int nt = 0; nt < 8; nt++)
      acc[nt] = __builtin_amdgcn_mfma_f32_16x16x32_bf16(af.s, bf[nt].s, acc[nt], 0, 0, 0);
    if (kt < 7){
#pragma unroll
      for (int nt = 0; nt < 8; nt++) bf[nt] = bn[nt];
    }
  }

  float sv[8], dv[8];
#pragma unroll
  for (int h = 0; h < 8; h++){ sv[h] = att_s[h * 16 + l16]; dv[h] = att_d[h * 16 + l16]; }
#pragma unroll
  for (int r = 0; r < 4; r++){
    const int gr = m0 + quad * 4 + r;
    float s[8], d[8];
#pragma unroll
    for (int h = 0; h < 8; h++){ s[h] = acc[h][r] * sv[h]; d[h] = acc[h][r] * dv[h]; }
#pragma unroll
    for (int o = 1; o < 16; o <<= 1){
#pragma unroll
      for (int h = 0; h < 8; h++){ s[h] += __shfl_xor(s[h], o); d[h] += __shfl_xor(d[h], o); }
    }
    if (gr < NN){
#pragma unroll
      for (int h = 0; h < 8; h++)
        h1b[(size_t)gr * HC + h * 16 + l16] = (unsigned short)f2bf(acc[h][r]);
      if (l16 == 0){
        *(float4*)(as1 + gr * 8)     = make_float4(s[0], s[1], s[2], s[3]);
        *(float4*)(as1 + gr * 8 + 4) = make_float4(s[4], s[5], s[6], s[7]);
        *(float4*)(ad1 + gr * 8)     = make_float4(d[0], d[1], d[2], d[3]);
        *(float4*)(ad1 + gr * 8 + 4) = make_float4(d[4], d[5], d[6], d[7]);
      }
    }
  }
}

// K2: layer-1 aggregate, TWO-PHASE lane-parallel softmax. One wave per node,
// 4 nodes/block. Phase A: lane e = edge e (lane deg = self-loop): parallel gather
// of attention scores, ONE wave max-reduce + ONE exp + sum-reduce -> weights in LDS.
// Phase B: lanes = 2 bf16 channels each; 17-iter independent-FMA gather over h1b
// rows, 4-deep pipelined. No online-softmax recurrence anywhere.
__global__ __launch_bounds__(256) void k_agg1(const int* __restrict__ srcp,
                                              const int* __restrict__ cnt,
                                              const float* __restrict__ as1,
                                              const float* __restrict__ ad1,
                                              const unsigned short* __restrict__ h1b,
                                              const float* __restrict__ b1,
                                              unsigned short* __restrict__ h2b){
  __shared__ float wls[4][8][65];   // [wave][head][edge], stride 65 -> bank h+e
  __shared__ int   sls[4][64];
  const int lane = threadIdx.x & 63, w = threadIdx.x >> 6;
  const int n = blockIdx.x * 4 + w;
  int deg = cnt[n]; if (deg > CAP - 1) deg = CAP - 1;   // reserve slot for self
  const int nE = deg + 1;
  const bool act = (lane <= deg);
  int sA = n;                                   // lane==deg -> self loop
  if (lane < deg) sA = srcp[n * CAP + lane];    // coalesced row read
  const float4 d0 = *(const float4*)(ad1 + (size_t)n * 8);
  const float4 d1 = *(const float4*)(ad1 + (size_t)n * 8 + 4);
  const float4 a0 = *(const float4*)(as1 + (size_t)sA * 8);
  const float4 a1 = *(const float4*)(as1 + (size_t)sA * 8 + 4);
  float v[8];
  v[0]=leaky(a0.x+d0.x); v[1]=leaky(a0.y+d0.y); v[2]=leaky(a0.z+d0.z); v[3]=leaky(a0.w+d0.w);
  v[4]=leaky(a1.x+d1.x); v[5]=leaky(a1.y+d1.y); v[6]=leaky(a1.z+d1.z); v[7]=leaky(a1.w+d1.w);
#pragma unroll
  for (int h = 0; h < 8; h++) if (!act) v[h] = -3.0e38f;
  float mx[8];
#pragma unroll
  for (int h = 0; h < 8; h++) mx[h] = v[h];
#pragma unroll
  for (int o = 1; o < 64; o <<= 1){
#pragma unroll
    for (int h = 0; h < 8; h++) mx[h] = fmaxf(mx[h], __shfl_xor(mx[h], o));
  }
  float wt[8], den[8];
#pragma unroll
  for (int h = 0; h < 8; h++) wt[h] = act ? __expf(v[h] - mx[h]) : 0.f;
#pragma unroll
  for (int h = 0; h < 8; h++) den[h] = wt[h];
#pragma unroll
  for (int o = 1; o < 64; o <<= 1){
#pragma unroll
    for (int h = 0; h < 8; h++) den[h] += __shfl_xor(den[h], o);
  }
#pragma unroll
  for (int h = 0; h < 8; h++) wls[w][h][lane] = wt[h];
  sls[w][lane] = sA;
  __syncthreads();

  // Phase B: lane -> channels {2*lane, 2*lane+1}, head = lane>>3.
  const int h = lane >> 3;
  float ax = 0.f, ay = 0.f;
  unsigned int u0, u1, u2, u3;
  float q0, q1, q2, q3;
  {
    const int i1 = min(1, deg), i2 = min(2, deg), i3 = min(3, deg);
    u0 = *(const unsigned int*)(h1b + (size_t)sls[w][0]  * HC + 2 * lane);
    u1 = *(const unsigned int*)(h1b + (size_t)sls[w][i1] * HC + 2 * lane);
    u2 = *(const unsigned int*)(h1b + (size_t)sls[w][i2] * HC + 2 * lane);
    u3 = *(const unsigned int*)(h1b + (size_t)sls[w][i3] * HC + 2 * lane);
    q0 = wls[w][h][0];
    q1 = (1 < nE) ? wls[w][h][1] : 0.f;
    q2 = (2 < nE) ? wls[w][h][2] : 0.f;
    q3 = (3 < nE) ? wls[w][h][3] : 0.f;
  }
  for (int i = 0; i < nE; i += 4){
    const int p0 = min(i + 4, deg), p1 = min(i + 5, deg);
    const int p2 = min(i + 6, deg), p3 = min(i + 7, deg);
    const unsigned int n0 = *(const unsigned int*)(h1b + (size_t)sls[w][p0] * HC + 2 * lane);
    const unsigned int n1 = *(const unsigned int*)(h1b + (size_t)sls[w][p1] * HC + 2 * lane);
    const unsigned int n2 = *(const unsigned int*)(h1b + (size_t)sls[w][p2] * HC + 2 * lane);
    const unsigned int n3 = *(const unsigned int*)(h1b + (size_t)sls[w][p3] * HC + 2 * lane);
    const float r0 = (i + 4 < nE) ? wls[w][h][p0] : 0.f;
    const float r1 = (i + 5 < nE) ? wls[w][h][p1] : 0.f;
    const float r2 = (i + 6 < nE) ? wls[w][h][p2] : 0.f;
    const float r3 = (i + 7 < nE) ? wls[w][h][p3] : 0.f;
    ax += q0 * bflo(u0); ay += q0 * bfhi(u0);
    ax += q1 * bflo(u1); ay += q1 * bfhi(u1);
    ax += q2 * bflo(u2); ay += q2 * bfhi(u2);
    ax += q3 * bflo(u3); ay += q3 * bfhi(u3);
    u0 = n0; u1 = n1; u2 = n2; u3 = n3;
    q0 = r0; q1 = r1; q2 = r2; q3 = r3;
  }
  const float invd = 1.f / (den[h] + 1e-16f);
  const float2 bb = *(const float2*)(b1 + 2 * lane);
  float ox = ax * invd + bb.x;
  float oy = ay * invd + bb.y;
  ox = ox > 0.f ? ox : (__expf(ox) - 1.f);   // ELU
  oy = oy > 0.f ? oy : (__expf(oy) - 1.f);
  *(unsigned int*)(h2b + (size_t)n * HC + 2 * lane) = pack2bf(ox, oy);
}

// K3: g(bf16)[N,40] = h2(bf16) @ W2; fused att2 dots.
__global__ __launch_bounds__(256) void k_gemm2(const unsigned short* __restrict__ h2b,
                                               const float* __restrict__ W2,
                                               const float* __restrict__ att_s2,
                                               const float* __restrict__ att_d2,
                                               unsigned short* __restrict__ gb,
                                               float* __restrict__ as2,
                                               float* __restrict__ ad2){
  __shared__ float hs[R2][HC + 2];
  __shared__ float w2s[HC * NC];
  const int tid = threadIdx.x;
  const int r0 = blockIdx.x * R2;
  for (int i = tid; i < HC * NC; i += 256) w2s[i] = W2[i];
  for (int i = tid; i < R2 * (HC / 2); i += 256){      // unpack bf16 pairs
    int r = i / (HC / 2), c = i % (HC / 2);
    unsigned int u = (r0 + r < NN) ? ((const unsigned int*)h2b)[(size_t)(r0 + r) * (HC / 2) + c] : 0u;
    hs[r][2 * c]     = bflo(u);
    hs[r][2 * c + 1] = bfhi(u);
  }
  __syncthreads();
  const int r = tid >> 3, j = tid & 7;
  float acc[5] = {0.f, 0.f, 0.f, 0.f, 0.f};
  for (int k = 0; k < HC; k++){
    float hv = hs[r][k];
#pragma unroll
    for (int q = 0; q < 5; q++) acc[q] += hv * w2s[k * NC + j + 8 * q];
  }
  const int node = r0 + r;
  if (node < NN){
    float s = 0.f, d = 0.f;
#pragma unroll
    for (int q = 0; q < 5; q++){
      int c = j + 8 * q;
      gb[(size_t)node * NC + c] = (unsigned short)f2bf(acc[q]);
      s += acc[q] * att_s2[c];
      d += acc[q] * att_d2[c];
    }
#pragma unroll
    for (int o = 1; o < 8; o <<= 1){ s += __shfl_xor(s, o); d += __shfl_xor(d, o); }
    if (j == 0){ as2[node] = s; ad2[node] = d; }
  }
}

// K4: layer-2 aggregate, TWO-PHASE lane-parallel softmax + log_softmax.
// Phase A: lane e = edge e (lane deg = self). Phase B: lane = class (40 active).
__global__ __launch_bounds__(256) void k_agg2(const int* __restrict__ srcp,
                                              const int* __restrict__ cnt,
                                              const float* __restrict__ as2,
                                              const float* __restrict__ ad2,
                                              const unsigned short* __restrict__ gb,
                                              const float* __restrict__ b2,
                                              float* __restrict__ out){
  __shared__ float wls[4][64];
  __shared__ int   sls[4][64];
  const int lane = threadIdx.x & 63, w = threadIdx.x >> 6;
  const int n = blockIdx.x * 4 + w;
  int deg = cnt[n]; if (deg > CAP - 1) deg = CAP - 1;   // reserve slot for self
  const int nE = deg + 1;
  const bool act = (lane <= deg);
  int sA = n;                                   // lane==deg -> self loop
  if (lane < deg) sA = srcp[n * CAP + lane];
  const float ad = ad2[n];
  float v = act ? leaky(as2[sA] + ad) : -3.0e38f;
  float mx = v;
#pragma unroll
  for (int o = 1; o < 64; o <<= 1) mx = fmaxf(mx, __shfl_xor(mx, o));
  float wt = act ? __expf(v - mx) : 0.f;
  float den = wt;
#pragma unroll
  for (int o = 1; o < 64; o <<= 1) den += __shfl_xor(den, o);
  wls[w][lane] = wt;
  sls[w][lane] = sA;
  __syncthreads();

  // Phase B: lane = class c (lanes 40..63 compute a dup of class 39, discarded)
  const int c = min(lane, NC - 1);
  float acc = 0.f;
  float g0, g1, g2, g3, q0, q1, q2, q3;
  {
    const int i1 = min(1, deg), i2 = min(2, deg), i3 = min(3, deg);
    g0 = bfus(gb[(size_t)sls[w][0]  * NC + c]);
    g1 = bfus(gb[(size_t)sls[w][i1] * NC + c]);
    g2 = bfus(gb[(size_t)sls[w][i2] * NC + c]);
    g3 = bfus(gb[(size_t)sls[w][i3] * NC + c]);
    q0 = wls[w][0];
    q1 = (1 < nE) ? wls[w][1] : 0.f;
    q2 = (2 < nE) ? wls[w][2] : 0.f;
    q3 = (3 < nE) ? wls[w][3] : 0.f;
  }
  for (int i = 0; i < nE; i += 4){
    const int p0 = min(i + 4, deg), p1 = min(i + 5, deg);
    const int p2 = min(i + 6, deg), p3 = min(i + 7, deg);
    const float h0 = bfus(gb[(size_t)sls[w][p0] * NC + c]);
    const float h1 = bfus(gb[(size_t)sls[w][p1] * NC + c]);
    const float h2 = bfus(gb[(size_t)sls[w][p2] * NC + c]);
    const float h3 = bfus(gb[(size_t)sls[w][p3] * NC + c]);
    const float r0 = (i + 4 < nE) ? wls[w][p0] : 0.f;
    const float r1 = (i + 5 < nE) ? wls[w][p1] : 0.f;
    const float r2 = (i + 6 < nE) ? wls[w][p2] : 0.f;
    const float r3 = (i + 7 < nE) ? wls[w][p3] : 0.f;
    acc += q0 * g0 + q1 * g1 + q2 * g2 + q3 * g3;
    g0 = h0; g1 = h1; g2 = h2; g3 = h3;
    q0 = r0; q1 = r1; q2 = r2; q3 = r3;
  }
  const float invd = 1.f / (den + 1e-16f);
  const bool cl = (lane < NC);
  float f = acc * invd + b2[c];
  if (cl) out[(size_t)n * NC + lane] = f;
  float fv = cl ? f : -3.4e38f;
  float m2 = fv;
#pragma unroll
  for (int o = 1; o < 64; o <<= 1) m2 = fmaxf(m2, __shfl_xor(m2, o));
  float ex = cl ? __expf(fv - m2) : 0.f;
#pragma unroll
  for (int o = 1; o < 64; o <<= 1) ex += __shfl_xor(ex, o);
  const float lse = m2 + __logf(ex);
  if (cl) out[(size_t)(NN * NC) + (size_t)n * NC + lane] = fv - lse;
}

extern "C" void kernel_launch(void* const* d_in, const int* in_sizes, int n_in,
                              void* d_out, int out_size, void* d_ws, size_t ws_size,
                              hipStream_t stream){
  const float* x      = (const float*)d_in[0];
  const int*   ei     = (const int*)  d_in[1];
  const float* W1     = (const float*)d_in[3];
  const float* att_s1 = (const float*)d_in[4];
  const float* att_d1 = (const float*)d_in[5];
  const float* b1     = (const float*)d_in[6];
  const float* W2     = (const float*)d_in[7];
  const float* att_s2 = (const float*)d_in[8];
  const float* att_d2 = (const float*)d_in[9];
  const float* b2     = (const float*)d_in[10];
  float* out = (float*)d_out;

  char* wp = (char*)d_ws;
  uint4* W1bfs = (uint4*)wp;                 wp += (size_t)4096 * 16;      // 64 KB
  unsigned short* h1b = (unsigned short*)wp; wp += (size_t)NN * HC * 2;    // 12.8 MB
  unsigned short* h2b = (unsigned short*)wp; wp += (size_t)NN * HC * 2;    // 12.8 MB
  unsigned short* gb  = (unsigned short*)wp; wp += (size_t)NN * NC * 2;    // 4 MB
  float* as1 = (float*)wp;                   wp += (size_t)NN * HD * 4;
  float* ad1 = (float*)wp;                   wp += (size_t)NN * HD * 4;
  float* as2 = (float*)wp;                   wp += (size_t)NN * 4;
  float* ad2 = (float*)wp;                   wp += (size_t)NN * 4;
  int* cnt   = (int*)wp;                     wp += (size_t)NN * 4;
  int* srcp  = (int*)wp;                     wp += (size_t)NN * CAP * 4;   // 12.8 MB

  hipMemsetAsync(cnt, 0, (size_t)NN * sizeof(int), stream);
  k_prep  <<<16 + SCB, 256, 0, stream>>>(W1, W1bfs, ei, cnt, srcp);
  k_gemm1 <<<GB1, 256, 0, stream>>>(x, W1bfs, att_s1, att_d1, h1b, as1, ad1);
  k_agg1  <<<NN / 4, 256, 0, stream>>>(srcp, cnt, as1, ad1, h1b, b1, h2b);
  k_gemm2 <<<(NN + R2 - 1) / R2, 256, 0, stream>>>(h2b, W2, att_s2, att_d2, gb, as2, ad2);
  k_agg2  <<<NN / 4, 256, 0, stream>>>(srcp, cnt, as2, ad2, gb, b2, out);
}

// Round 5
// 259.820 us; speedup vs baseline: 1.2259x; 1.1215x over previous
//
#include <hip/hip_runtime.h>

#define NN 50000
#define EE 800000
#define FIN 256
#define HD 8
#define C1 16
#define HC 128         // HD*C1
#define NC 40
#define NEG 0.2f
#define CAP 64         // ELL capacity per node; P(Poisson(16) >= 64) ~ 1e-17
#define R2 32          // rows per block in k_gemm2
#define BM 64          // k_gemm1 row tile (4 waves x 16 rows)
#define GB1 ((NN + BM - 1) / BM)  // 782 pure-GEMM blocks
#define NP_N (NN / 8)  // nodes per partition (6250)
#define SCB 2048       // scatter blocks (8 partitions x 256 ranks)

typedef __attribute__((ext_vector_type(8))) short short8;   // 8 bf16 (4 VGPRs)
typedef __attribute__((ext_vector_type(4))) float f32x4;    // MFMA C/D
union FragU { uint4 u; short8 s; };

__device__ __forceinline__ float leaky(float v){ return v > 0.f ? v : NEG * v; }

// fp32 -> bf16 round-to-nearest-even (no NaNs in this workload)
__device__ __forceinline__ unsigned int f2bf(float f){
  unsigned int u = __float_as_uint(f);
  u += 0x7fffu + ((u >> 16) & 1u);
  return u >> 16;
}
__device__ __forceinline__ unsigned int pack2bf(float a, float b){
  return f2bf(a) | (f2bf(b) << 16);
}
__device__ __forceinline__ float bflo(unsigned int u){ return __uint_as_float(u << 16); }
__device__ __forceinline__ float bfhi(unsigned int u){ return __uint_as_float(u & 0xffff0000u); }
__device__ __forceinline__ float bfus(unsigned short u){ return __uint_as_float((unsigned int)u << 16); }

// K0: blocks 0..15 swizzle W1 into MFMA B-fragment order; blocks 16..2063 run the
// XCD-partitioned ELL scatter at HIGH occupancy. Partition p = b&7 matches the XCD
// the block lands on (round-robin dispatch), so cnt/srcp atomics stay XCD-L2-local.
__global__ __launch_bounds__(256) void k_prep(const float* __restrict__ W1,
                                              uint4* __restrict__ W1bfs,
                                              const int* __restrict__ ei,
                                              int* __restrict__ cnt,
                                              int* __restrict__ srcp){
  const int tid = threadIdx.x;
  if (blockIdx.x < 16){
    int f = blockIdx.x * 256 + tid;   // 0..4095
    int lane = f & 63, nt = (f >> 6) & 7, kt = f >> 9;
    int quad = lane >> 4, l16 = lane & 15;
    const float* src = W1 + (size_t)(kt * 32 + quad * 8) * HC + nt * 16 + l16;
    unsigned int p[4];
#pragma unroll
    for (int jj = 0; jj < 4; jj++){
      float v0 = src[(size_t)(2 * jj) * HC];
      float v1 = src[(size_t)(2 * jj + 1) * HC];
      p[jj] = pack2bf(v0, v1);
    }
    W1bfs[f] = make_uint4(p[0], p[1], p[2], p[3]);
    return;
  }
  const int b = blockIdx.x - 16;          // 0..2047 (16%8==0 keeps b&7 == XCD id)
  const int part = b & 7, rank = b >> 3;  // rank 0..255
  const int lo = part * NP_N, hi = lo + NP_N;
  for (int e = rank * 256 + tid; e < EE; e += 256 * 256){
    int d = ei[EE + e];
    if (d >= lo && d < hi){
      int s = ei[e];
      int pos = atomicAdd(&cnt[d], 1);
      if (pos < CAP) srcp[d * CAP + pos] = s;   // clamp guard (never hit per Poisson tail)
    }
  }
}

// K1: PURE GEMM h1(bf16)[N,128] = x @ W1 via bf16 MFMA 16x16x32. No LDS, no barriers.
__global__ __launch_bounds__(256, 3) void k_gemm1(const float* __restrict__ x,
                                                  const uint4* __restrict__ W1bfs,
                                                  const float* __restrict__ att_s,
                                                  const float* __restrict__ att_d,
                                                  unsigned short* __restrict__ h1b,
                                                  float* __restrict__ as1,
                                                  float* __restrict__ ad1){
  const int tid = threadIdx.x;
  const int wave = tid >> 6, lane = tid & 63;
  const int quad = lane >> 4, l16 = lane & 15;
  const int m0 = blockIdx.x * BM + wave * 16;
  int arow = m0 + l16; if (arow >= NN) arow = NN - 1;   // clamp (dup rows benign)
  const float* xr = x + (size_t)arow * FIN;

  float4 xa[16];
#pragma unroll
  for (int kt = 0; kt < 8; kt++){
    xa[2 * kt]     = *(const float4*)(xr + kt * 32 + quad * 8);
    xa[2 * kt + 1] = *(const float4*)(xr + kt * 32 + quad * 8 + 4);
  }
  FragU bf[8];
#pragma unroll
  for (int nt = 0; nt < 8; nt++) bf[nt].u = W1bfs[nt * 64 + lane];

  f32x4 acc[8];
#pragma unroll
  for (int t = 0; t < 8; t++) acc[t] = (f32x4){0.f, 0.f, 0.f, 0.f};

#pragma unroll
  for (int kt = 0; kt < 8; kt++){
    FragU bn[8];
    if (kt < 7){
#pragma unroll
      for (int nt = 0; nt < 8; nt++)
        bn[nt].u = W1bfs[((kt + 1) * 8 + nt) * 64 + lane];
    }
    FragU af;
    af.u = make_uint4(pack2bf(xa[2 * kt].x,     xa[2 * kt].y),
                      pack2bf(xa[2 * kt].z,     xa[2 * kt].w),
                      pack2bf(xa[2 * kt + 1].x, xa[2 * kt + 1].y),
                      pack2bf(xa[2 * kt + 1].z, xa[2 * kt + 1].w));
#pragma unroll
    for (int nt = 0; nt < 8; nt++)
      acc[nt] = __builtin_amdgcn_mfma_f32_16x16x32_bf16(af.s, bf[nt].s, acc[nt], 0, 0, 0);
    if (kt < 7){
#pragma unroll
      for (int nt = 0; nt < 8; nt++) bf[nt] = bn[nt];
    }
  }

  float sv[8], dv[8];
#pragma unroll
  for (int h = 0; h < 8; h++){ sv[h] = att_s[h * 16 + l16]; dv[h] = att_d[h * 16 + l16]; }
#pragma unroll
  for (int r = 0; r < 4; r++){
    const int gr = m0 + quad * 4 + r;
    float s[8], d[8];
#pragma unroll
    for (int h = 0; h < 8; h++){ s[h] = acc[h][r] * sv[h]; d[h] = acc[h][r] * dv[h]; }
#pragma unroll
    for (int o = 1; o < 16; o <<= 1){
#pragma unroll
      for (int h = 0; h < 8; h++){ s[h] += __shfl_xor(s[h], o); d[h] += __shfl_xor(d[h], o); }
    }
    if (gr < NN){
#pragma unroll
      for (int h = 0; h < 8; h++)
        h1b[(size_t)gr * HC + h * 16 + l16] = (unsigned short)f2bf(acc[h][r]);
      if (l16 == 0){
        *(float4*)(as1 + gr * 8)     = make_float4(s[0], s[1], s[2], s[3]);
        *(float4*)(as1 + gr * 8 + 4) = make_float4(s[4], s[5], s[6], s[7]);
        *(float4*)(ad1 + gr * 8)     = make_float4(d[0], d[1], d[2], d[3]);
        *(float4*)(ad1 + gr * 8 + 4) = make_float4(d[4], d[5], d[6], d[7]);
      }
    }
  }
}

// K2: layer-1 aggregate. One wave per node, 4 nodes/block, NO barriers (all LDS
// traffic is intra-wave). Phase A: lane = (head, edge-slot) = (lane>>3, lane&7);
// each lane covers edges {e8, e8+8, ...} of its head -> max/sum butterflies are
// 3 steps with ONE value per lane (6 cross-lane ops total, was 96). Two passes
// through wls (v, then wt) avoid runtime-indexed register arrays.
// Phase B: lane = 2 bf16 channels; 16 independent payload loads in flight
// (static prefetch), 8-wide batched tail for deg >= 16.
__global__ __launch_bounds__(256) void k_agg1(const int* __restrict__ srcp,
                                              const int* __restrict__ cnt,
                                              const float* __restrict__ as1,
                                              const float* __restrict__ ad1,
                                              const unsigned short* __restrict__ h1b,
                                              const float* __restrict__ b1,
                                              unsigned short* __restrict__ h2b){
  __shared__ float wls[4][64][8];   // [wave][edge][head]: bank (8*e8+h)%32 -> 2-way, free
  __shared__ int   sls[4][64];
  const int lane = threadIdx.x & 63, w = threadIdx.x >> 6;
  const int n = blockIdx.x * 4 + w;
  int deg = cnt[n]; if (deg > CAP - 1) deg = CAP - 1;   // reserve slot for self
  const int nE = deg + 1;
  int sA = n;                                   // lanes >= deg hold self id
  if (lane < deg) sA = srcp[n * CAP + lane];    // coalesced row read
  sls[w][lane] = sA;                            // sls[j] == n for all j >= deg

  const int h = lane >> 3, e8 = lane & 7;
  const float adg = ad1[n * 8 + h];
  int nCh = (nE + 7) >> 3; if (nCh < 2) nCh = 2;   // cover i<16 so Phase B is guard-free

  // pass 1: scores -> LDS, per-lane running max over this lane's edge slots
  float mx = -3.0e38f;
  for (int c = 0; c < nCh; c++){
    const int i = c * 8 + e8;
    const int s = sls[w][i];
    const float v = (i < nE) ? leaky(as1[(size_t)s * 8 + h] + adg) : -3.0e38f;
    wls[w][i][h] = v;
    mx = fmaxf(mx, v);
  }
  mx = fmaxf(mx, __shfl_xor(mx, 1));
  mx = fmaxf(mx, __shfl_xor(mx, 2));
  mx = fmaxf(mx, __shfl_xor(mx, 4));   // per-head max, broadcast in 8-lane group

  // pass 2: weights -> LDS, per-head denominator
  float den = 0.f;
  for (int c = 0; c < nCh; c++){
    const int i = c * 8 + e8;
    const float v = wls[w][i][h];
    const float wt = (i < nE) ? __expf(v - mx) : 0.f;
    wls[w][i][h] = wt;
    den += wt;
  }
  den += __shfl_xor(den, 1);
  den += __shfl_xor(den, 2);
  den += __shfl_xor(den, 4);           // lane's den is for head lane>>3 (matches Phase B)

  // Phase B: lane -> channels {2*lane, 2*lane+1}, head = lane>>3 (same h as above).
  const unsigned int* hp = (const unsigned int*)h1b;   // h1b as dwords: row = s*64
  float ax = 0.f, ay = 0.f;
  {
    unsigned int u[16]; float q[16];
#pragma unroll
    for (int i = 0; i < 16; i++){
      u[i] = hp[(size_t)(unsigned)((sls[w][i] << 6) + lane)];
      q[i] = wls[w][i][h];                 // ==0 for i >= nE (pass 2 wrote zeros)
    }
#pragma unroll
    for (int i = 0; i < 16; i++){ ax += q[i] * bflo(u[i]); ay += q[i] * bfhi(u[i]); }
  }
  for (int i0 = 16; i0 < nE; i0 += 8){     // wave-uniform branch; typically 0-1 rounds
    unsigned int uu[8]; float qq[8];
#pragma unroll
    for (int t = 0; t < 8; t++){
      const int j = i0 + t, p = min(j, deg);
      uu[t] = hp[(size_t)(unsigned)((sls[w][p] << 6) + lane)];
      qq[t] = (j < nE) ? wls[w][p][h] : 0.f;
    }
#pragma unroll
    for (int t = 0; t < 8; t++){ ax += qq[t] * bflo(uu[t]); ay += qq[t] * bfhi(uu[t]); }
  }

  const float invd = 1.f / (den + 1e-16f);
  const float2 bb = *(const float2*)(b1 + 2 * lane);
  float ox = ax * invd + bb.x;
  float oy = ay * invd + bb.y;
  ox = ox > 0.f ? ox : (__expf(ox) - 1.f);   // ELU
  oy = oy > 0.f ? oy : (__expf(oy) - 1.f);
  *(unsigned int*)(h2b + (size_t)n * HC + 2 * lane) = pack2bf(ox, oy);
}

// K3: g(bf16)[N,40] = h2(bf16) @ W2; fused att2 dots.
__global__ __launch_bounds__(256) void k_gemm2(const unsigned short* __restrict__ h2b,
                                               const float* __restrict__ W2,
                                               const float* __restrict__ att_s2,
                                               const float* __restrict__ att_d2,
                                               unsigned short* __restrict__ gb,
                                               float* __restrict__ as2,
                                               float* __restrict__ ad2){
  __shared__ float hs[R2][HC + 2];
  __shared__ float w2s[HC * NC];
  const int tid = threadIdx.x;
  const int r0 = blockIdx.x * R2;
  for (int i = tid; i < HC * NC; i += 256) w2s[i] = W2[i];
  for (int i = tid; i < R2 * (HC / 2); i += 256){      // unpack bf16 pairs
    int r = i / (HC / 2), c = i % (HC / 2);
    unsigned int u = (r0 + r < NN) ? ((const unsigned int*)h2b)[(size_t)(r0 + r) * (HC / 2) + c] : 0u;
    hs[r][2 * c]     = bflo(u);
    hs[r][2 * c + 1] = bfhi(u);
  }
  __syncthreads();
  const int r = tid >> 3, j = tid & 7;
  float acc[5] = {0.f, 0.f, 0.f, 0.f, 0.f};
  for (int k = 0; k < HC; k++){
    float hv = hs[r][k];
#pragma unroll
    for (int q = 0; q < 5; q++) acc[q] += hv * w2s[k * NC + j + 8 * q];
  }
  const int node = r0 + r;
  if (node < NN){
    float s = 0.f, d = 0.f;
#pragma unroll
    for (int q = 0; q < 5; q++){
      int c = j + 8 * q;
      gb[(size_t)node * NC + c] = (unsigned short)f2bf(acc[q]);
      s += acc[q] * att_s2[c];
      d += acc[q] * att_d2[c];
    }
#pragma unroll
    for (int o = 1; o < 8; o <<= 1){ s += __shfl_xor(s, o); d += __shfl_xor(d, o); }
    if (j == 0){ as2[node] = s; ad2[node] = d; }
  }
}

// K4: layer-2 aggregate, two-phase lane-parallel softmax + log_softmax. One wave
// per node, 4 nodes/block, NO barriers (intra-wave LDS only). Phase A: lane = edge.
// Phase B: lane = class; static-16 prefetch + 8-wide tail, fully guard-free
// (wls[j] == 0 for j > deg by construction).
__global__ __launch_bounds__(256) void k_agg2(const int* __restrict__ srcp,
                                              const int* __restrict__ cnt,
                                              const float* __restrict__ as2,
                                              const float* __restrict__ ad2,
                                              const unsigned short* __restrict__ gb,
                                              const float* __restrict__ b2,
                                              float* __restrict__ out){
  __shared__ float wls[4][64];
  __shared__ int   sls[4][64];
  const int lane = threadIdx.x & 63, w = threadIdx.x >> 6;
  const int n = blockIdx.x * 4 + w;
  int deg = cnt[n]; if (deg > CAP - 1) deg = CAP - 1;   // reserve slot for self
  const int nE = deg + 1;
  const bool act = (lane <= deg);
  int sA = n;                                   // lane==deg -> self loop; lanes>deg -> n
  if (lane < deg) sA = srcp[n * CAP + lane];
  sls[w][lane] = sA;
  const float ad = ad2[n];
  float v = act ? leaky(as2[sA] + ad) : -3.0e38f;
  float mx = v;
#pragma unroll
  for (int o = 1; o < 64; o <<= 1) mx = fmaxf(mx, __shfl_xor(mx, o));
  float wt = act ? __expf(v - mx) : 0.f;
  float den = wt;
#pragma unroll
  for (int o = 1; o < 64; o <<= 1) den += __shfl_xor(den, o);
  wls[w][lane] = wt;                            // 0 for lanes > deg

  // Phase B: lane = class c (lanes 40..63 dup class 39, discarded)
  const int c = min(lane, NC - 1);
  float acc = 0.f;
  {
    float g[16], q[16];
#pragma unroll
    for (int i = 0; i < 16; i++){
      g[i] = bfus(gb[(size_t)(unsigned)(sls[w][i] * NC + c)]);
      q[i] = wls[w][i];                         // 0 beyond nE
    }
#pragma unroll
    for (int i = 0; i < 16; i++) acc += q[i] * g[i];
  }
  for (int i0 = 16; i0 < nE; i0 += 8){          // wave-uniform; j <= 63 always
    float gg[8], qq[8];
#pragma unroll
    for (int t = 0; t < 8; t++){
      const int j = i0 + t;
      gg[t] = bfus(gb[(size_t)(unsigned)(sls[w][j] * NC + c)]);
      qq[t] = wls[w][j];                        // 0 beyond nE
    }
#pragma unroll
    for (int t = 0; t < 8; t++) acc += qq[t] * gg[t];
  }
  const float invd = 1.f / (den + 1e-16f);
  const bool cl = (lane < NC);
  float f = acc * invd + b2[c];
  if (cl) out[(size_t)n * NC + lane] = f;
  float fv = cl ? f : -3.4e38f;
  float m2 = fv;
#pragma unroll
  for (int o = 1; o < 64; o <<= 1) m2 = fmaxf(m2, __shfl_xor(m2, o));
  float ex = cl ? __expf(fv - m2) : 0.f;
#pragma unroll
  for (int o = 1; o < 64; o <<= 1) ex += __shfl_xor(ex, o);
  const float lse = m2 + __logf(ex);
  if (cl) out[(size_t)(NN * NC) + (size_t)n * NC + lane] = fv - lse;
}

extern "C" void kernel_launch(void* const* d_in, const int* in_sizes, int n_in,
                              void* d_out, int out_size, void* d_ws, size_t ws_size,
                              hipStream_t stream){
  const float* x      = (const float*)d_in[0];
  const int*   ei     = (const int*)  d_in[1];
  const float* W1     = (const float*)d_in[3];
  const float* att_s1 = (const float*)d_in[4];
  const float* att_d1 = (const float*)d_in[5];
  const float* b1     = (const float*)d_in[6];
  const float* W2     = (const float*)d_in[7];
  const float* att_s2 = (const float*)d_in[8];
  const float* att_d2 = (const float*)d_in[9];
  const float* b2     = (const float*)d_in[10];
  float* out = (float*)d_out;

  char* wp = (char*)d_ws;
  uint4* W1bfs = (uint4*)wp;                 wp += (size_t)4096 * 16;      // 64 KB
  unsigned short* h1b = (unsigned short*)wp; wp += (size_t)NN * HC * 2;    // 12.8 MB
  unsigned short* h2b = (unsigned short*)wp; wp += (size_t)NN * HC * 2;    // 12.8 MB
  unsigned short* gb  = (unsigned short*)wp; wp += (size_t)NN * NC * 2;    // 4 MB
  float* as1 = (float*)wp;                   wp += (size_t)NN * HD * 4;
  float* ad1 = (float*)wp;                   wp += (size_t)NN * HD * 4;
  float* as2 = (float*)wp;                   wp += (size_t)NN * 4;
  float* ad2 = (float*)wp;                   wp += (size_t)NN * 4;
  int* cnt   = (int*)wp;                     wp += (size_t)NN * 4;
  int* srcp  = (int*)wp;                     wp += (size_t)NN * CAP * 4;   // 12.8 MB

  hipMemsetAsync(cnt, 0, (size_t)NN * sizeof(int), stream);
  k_prep  <<<16 + SCB, 256, 0, stream>>>(W1, W1bfs, ei, cnt, srcp);
  k_gemm1 <<<GB1, 256, 0, stream>>>(x, W1bfs, att_s1, att_d1, h1b, as1, ad1);
  k_agg1  <<<NN / 4, 256, 0, stream>>>(srcp, cnt, as1, ad1, h1b, b1, h2b);
  k_gemm2 <<<(NN + R2 - 1) / R2, 256, 0, stream>>>(h2b, W2, att_s2, att_d2, gb, as2, ad2);
  k_agg2  <<<NN / 4, 256, 0, stream>>>(srcp, cnt, as2, ad2, gb, b2, out);
}

// Round 6
// 254.399 us; speedup vs baseline: 1.2520x; 1.0213x over previous
//
#include <hip/hip_runtime.h>

#define NN 50000
#define EE 800000
#define FIN 256
#define HD 8
#define C1 16
#define HC 128         // HD*C1
#define NC 40
#define NEG 0.2f
#define CAP 64         // ELL capacity per node; P(Poisson(16) >= 64) ~ 1e-17
#define R2 32          // rows per block in k_gemm2
#define BM 64          // k_gemm1 row tile (4 waves x 16 rows)
#define GB1 ((NN + BM - 1) / BM)  // 782 pure-GEMM blocks
#define NP_N (NN / 8)  // nodes per partition (6250)
#define SCB 2048       // scatter blocks (8 partitions x 256 ranks), appended to k_gemm1

typedef __attribute__((ext_vector_type(8))) short short8;   // 8 bf16 (4 VGPRs)
typedef __attribute__((ext_vector_type(4))) float f32x4;    // MFMA C/D
union FragU { uint4 u; short8 s; };

__device__ __forceinline__ float leaky(float v){ return v > 0.f ? v : NEG * v; }

// fp32 -> bf16 round-to-nearest-even (no NaNs in this workload)
__device__ __forceinline__ unsigned int f2bf(float f){
  unsigned int u = __float_as_uint(f);
  u += 0x7fffu + ((u >> 16) & 1u);
  return u >> 16;
}
__device__ __forceinline__ unsigned int pack2bf(float a, float b){
  return f2bf(a) | (f2bf(b) << 16);
}
__device__ __forceinline__ float bflo(unsigned int u){ return __uint_as_float(u << 16); }
__device__ __forceinline__ float bfhi(unsigned int u){ return __uint_as_float(u & 0xffff0000u); }
__device__ __forceinline__ float bfus(unsigned short u){ return __uint_as_float((unsigned int)u << 16); }

// K0: swizzle W1 (fp32 [256][128]) into MFMA B-fragment order (16 blocks only; the
// scatter moved into k_gemm1's dispatch as extra blocks so it overlaps the GEMM).
__global__ __launch_bounds__(256) void k_prep(const float* __restrict__ W1,
                                              uint4* __restrict__ W1bfs){
  int f = blockIdx.x * 256 + threadIdx.x;   // 0..4095
  int lane = f & 63, nt = (f >> 6) & 7, kt = f >> 9;
  int quad = lane >> 4, l16 = lane & 15;
  const float* src = W1 + (size_t)(kt * 32 + quad * 8) * HC + nt * 16 + l16;
  unsigned int p[4];
#pragma unroll
  for (int jj = 0; jj < 4; jj++){
    float v0 = src[(size_t)(2 * jj) * HC];
    float v1 = src[(size_t)(2 * jj + 1) * HC];
    p[jj] = pack2bf(v0, v1);
  }
  W1bfs[f] = make_uint4(p[0], p[1], p[2], p[3]);
}

// K1: block-partitioned dispatch. Blocks 0..GB1-1: pure MFMA GEMM (straight-line,
// no LDS, no barriers). Blocks GB1..GB1+SCB-1: XCD-partitioned ELL edge scatter.
// The two workloads are independent -> they co-schedule on the CUs, so the
// dispatch runs at ~max(T_gemm, T_scatter) instead of the serial sum.
// Scatter coverage: 2048 contiguous blockIdx values -> each residue (blockIdx&7)
// gets exactly 256 ranks ((blockIdx-GB1)>>3 in 0..255) -> every partition scans
// all 800k edges exactly once.
__global__ __launch_bounds__(256, 3) void k_gemm1(const float* __restrict__ x,
                                                  const uint4* __restrict__ W1bfs,
                                                  const float* __restrict__ att_s,
                                                  const float* __restrict__ att_d,
                                                  const int* __restrict__ ei,
                                                  unsigned short* __restrict__ h1b,
                                                  float* __restrict__ as1,
                                                  float* __restrict__ ad1,
                                                  int* __restrict__ cnt,
                                                  int* __restrict__ srcp){
  const int tid = threadIdx.x;
  if (blockIdx.x >= GB1){   // ---- scatter block ----
    const int part = blockIdx.x & 7, rank = (blockIdx.x - GB1) >> 3;
    const int lo = part * NP_N, hi = lo + NP_N;
    for (int e = rank * 256 + tid; e < EE; e += 256 * 256){
      int d = ei[EE + e];
      if (d >= lo && d < hi){
        int s = ei[e];
        int pos = atomicAdd(&cnt[d], 1);
        if (pos < CAP) srcp[d * CAP + pos] = s;   // clamp guard (never hit per Poisson tail)
      }
    }
    return;
  }
  // ---- GEMM block ----
  const int wave = tid >> 6, lane = tid & 63;
  const int quad = lane >> 4, l16 = lane & 15;
  const int m0 = blockIdx.x * BM + wave * 16;
  int arow = m0 + l16; if (arow >= NN) arow = NN - 1;   // clamp (dup rows benign)
  const float* xr = x + (size_t)arow * FIN;

  float4 xa[16];
#pragma unroll
  for (int kt = 0; kt < 8; kt++){
    xa[2 * kt]     = *(const float4*)(xr + kt * 32 + quad * 8);
    xa[2 * kt + 1] = *(const float4*)(xr + kt * 32 + quad * 8 + 4);
  }
  FragU bf[8];
#pragma unroll
  for (int nt = 0; nt < 8; nt++) bf[nt].u = W1bfs[nt * 64 + lane];

  f32x4 acc[8];
#pragma unroll
  for (int t = 0; t < 8; t++) acc[t] = (f32x4){0.f, 0.f, 0.f, 0.f};

#pragma unroll
  for (int kt = 0; kt < 8; kt++){
    FragU bn[8];
    if (kt < 7){
#pragma unroll
      for (int nt = 0; nt < 8; nt++)
        bn[nt].u = W1bfs[((kt + 1) * 8 + nt) * 64 + lane];
    }
    FragU af;
    af.u = make_uint4(pack2bf(xa[2 * kt].x,     xa[2 * kt].y),
                      pack2bf(xa[2 * kt].z,     xa[2 * kt].w),
                      pack2bf(xa[2 * kt + 1].x, xa[2 * kt + 1].y),
                      pack2bf(xa[2 * kt + 1].z, xa[2 * kt + 1].w));
#pragma unroll
    for (int nt = 0; nt < 8; nt++)
      acc[nt] = __builtin_amdgcn_mfma_f32_16x16x32_bf16(af.s, bf[nt].s, acc[nt], 0, 0, 0);
    if (kt < 7){
#pragma unroll
      for (int nt = 0; nt < 8; nt++) bf[nt] = bn[nt];
    }
  }

  float sv[8], dv[8];
#pragma unroll
  for (int h = 0; h < 8; h++){ sv[h] = att_s[h * 16 + l16]; dv[h] = att_d[h * 16 + l16]; }
#pragma unroll
  for (int r = 0; r < 4; r++){
    const int gr = m0 + quad * 4 + r;
    float s[8], d[8];
#pragma unroll
    for (int h = 0; h < 8; h++){ s[h] = acc[h][r] * sv[h]; d[h] = acc[h][r] * dv[h]; }
#pragma unroll
    for (int o = 1; o < 16; o <<= 1){
#pragma unroll
      for (int h = 0; h < 8; h++){ s[h] += __shfl_xor(s[h], o); d[h] += __shfl_xor(d[h], o); }
    }
    if (gr < NN){
#pragma unroll
      for (int h = 0; h < 8; h++)
        h1b[(size_t)gr * HC + h * 16 + l16] = (unsigned short)f2bf(acc[h][r]);
      if (l16 == 0){
        *(float4*)(as1 + gr * 8)     = make_float4(s[0], s[1], s[2], s[3]);
        *(float4*)(as1 + gr * 8 + 4) = make_float4(s[4], s[5], s[6], s[7]);
        *(float4*)(ad1 + gr * 8)     = make_float4(d[0], d[1], d[2], d[3]);
        *(float4*)(ad1 + gr * 8 + 4) = make_float4(d[4], d[5], d[6], d[7]);
      }
    }
  }
}

// K2: layer-1 aggregate. One wave per node, 8 nodes / 512-thread block, NO barriers
// (all LDS traffic intra-wave). Phase A: lane = (head, edge-slot); 3-step butterflies.
// Phase B: lane = 2 bf16 channels; static-16 prefetch + 8-wide tail.
// sls holds PRE-SCALED row offsets (s<<6, dword index) to trim per-load address math.
__global__ __launch_bounds__(512) void k_agg1(const int* __restrict__ srcp,
                                              const int* __restrict__ cnt,
                                              const float* __restrict__ as1,
                                              const float* __restrict__ ad1,
                                              const unsigned short* __restrict__ h1b,
                                              const float* __restrict__ b1,
                                              unsigned short* __restrict__ h2b){
  __shared__ float wls[8][64][8];   // [wave][edge][head]
  __shared__ int   sls[8][64];      // pre-scaled: s<<6 (dword row base in h1b)
  const int lane = threadIdx.x & 63, w = threadIdx.x >> 6;
  const int n = blockIdx.x * 8 + w;
  int deg = cnt[n]; if (deg > CAP - 1) deg = CAP - 1;   // reserve slot for self
  const int nE = deg + 1;
  int sA = n;                                   // lanes >= deg hold self id
  if (lane < deg) sA = srcp[n * CAP + lane];    // coalesced row read
  sls[w][lane] = sA << 6;                       // sls[j] == n<<6 for all j >= deg

  const int h = lane >> 3, e8 = lane & 7;
  const float adg = ad1[n * 8 + h];
  int nCh = (nE + 7) >> 3; if (nCh < 2) nCh = 2;   // cover i<16 so Phase B is guard-free

  // pass 1: scores -> LDS, per-lane running max over this lane's edge slots
  float mx = -3.0e38f;
  for (int c = 0; c < nCh; c++){
    const int i = c * 8 + e8;
    const int s8 = sls[w][i] >> 3;               // == s*8
    const float v = (i < nE) ? leaky(as1[(size_t)(unsigned)(s8 + h)] + adg) : -3.0e38f;
    wls[w][i][h] = v;
    mx = fmaxf(mx, v);
  }
  mx = fmaxf(mx, __shfl_xor(mx, 1));
  mx = fmaxf(mx, __shfl_xor(mx, 2));
  mx = fmaxf(mx, __shfl_xor(mx, 4));   // per-head max, broadcast in 8-lane group

  // pass 2: weights -> LDS, per-head denominator
  float den = 0.f;
  for (int c = 0; c < nCh; c++){
    const int i = c * 8 + e8;
    const float v = wls[w][i][h];
    const float wt = (i < nE) ? __expf(v - mx) : 0.f;
    wls[w][i][h] = wt;
    den += wt;
  }
  den += __shfl_xor(den, 1);
  den += __shfl_xor(den, 2);
  den += __shfl_xor(den, 4);           // lane's den is for head lane>>3 (matches Phase B)

  // Phase B: lane -> channels {2*lane, 2*lane+1}, head = lane>>3 (same h as above).
  const unsigned int* hp = (const unsigned int*)h1b;   // h1b as dwords: row = s*64
  float ax = 0.f, ay = 0.f;
  {
    unsigned int u[16]; float q[16];
#pragma unroll
    for (int i = 0; i < 16; i++){
      u[i] = hp[(size_t)(unsigned)(sls[w][i] + lane)];
      q[i] = wls[w][i][h];                 // ==0 for i >= nE (pass 2 wrote zeros)
    }
#pragma unroll
    for (int i = 0; i < 16; i++){ ax += q[i] * bflo(u[i]); ay += q[i] * bfhi(u[i]); }
  }
  for (int i0 = 16; i0 < nE; i0 += 8){     // wave-uniform; j = i0+t <= 63 always
    unsigned int uu[8]; float qq[8];
#pragma unroll
    for (int t = 0; t < 8; t++){
      const int j = i0 + t;
      uu[t] = hp[(size_t)(unsigned)(sls[w][j] + lane)];
      qq[t] = (j < nE) ? wls[w][j][h] : 0.f;
    }
#pragma unroll
    for (int t = 0; t < 8; t++){ ax += qq[t] * bflo(uu[t]); ay += qq[t] * bfhi(uu[t]); }
  }

  const float invd = 1.f / (den + 1e-16f);
  const float2 bb = *(const float2*)(b1 + 2 * lane);
  float ox = ax * invd + bb.x;
  float oy = ay * invd + bb.y;
  ox = ox > 0.f ? ox : (__expf(ox) - 1.f);   // ELU
  oy = oy > 0.f ? oy : (__expf(oy) - 1.f);
  *(unsigned int*)(h2b + (size_t)n * HC + 2 * lane) = pack2bf(ox, oy);
}

// K3: g(bf16)[N,40] = h2(bf16) @ W2; fused att2 dots.
__global__ __launch_bounds__(256) void k_gemm2(const unsigned short* __restrict__ h2b,
                                               const float* __restrict__ W2,
                                               const float* __restrict__ att_s2,
                                               const float* __restrict__ att_d2,
                                               unsigned short* __restrict__ gb,
                                               float* __restrict__ as2,
                                               float* __restrict__ ad2){
  __shared__ float hs[R2][HC + 2];
  __shared__ float w2s[HC * NC];
  const int tid = threadIdx.x;
  const int r0 = blockIdx.x * R2;
  for (int i = tid; i < HC * NC; i += 256) w2s[i] = W2[i];
  for (int i = tid; i < R2 * (HC / 2); i += 256){      // unpack bf16 pairs
    int r = i / (HC / 2), c = i % (HC / 2);
    unsigned int u = (r0 + r < NN) ? ((const unsigned int*)h2b)[(size_t)(r0 + r) * (HC / 2) + c] : 0u;
    hs[r][2 * c]     = bflo(u);
    hs[r][2 * c + 1] = bfhi(u);
  }
  __syncthreads();
  const int r = tid >> 3, j = tid & 7;
  float acc[5] = {0.f, 0.f, 0.f, 0.f, 0.f};
  for (int k = 0; k < HC; k++){
    float hv = hs[r][k];
#pragma unroll
    for (int q = 0; q < 5; q++) acc[q] += hv * w2s[k * NC + j + 8 * q];
  }
  const int node = r0 + r;
  if (node < NN){
    float s = 0.f, d = 0.f;
#pragma unroll
    for (int q = 0; q < 5; q++){
      int c = j + 8 * q;
      gb[(size_t)node * NC + c] = (unsigned short)f2bf(acc[q]);
      s += acc[q] * att_s2[c];
      d += acc[q] * att_d2[c];
    }
#pragma unroll
    for (int o = 1; o < 8; o <<= 1){ s += __shfl_xor(s, o); d += __shfl_xor(d, o); }
    if (j == 0){ as2[node] = s; ad2[node] = d; }
  }
}

// K4: layer-2 aggregate, two-phase lane-parallel softmax + log_softmax. One wave
// per node, 8 nodes / 512-thread block, NO barriers. Phase A: lane = edge.
// Phase B: lane = class; static-16 prefetch + 8-wide tail. sls pre-scaled (s*NC).
__global__ __launch_bounds__(512) void k_agg2(const int* __restrict__ srcp,
                                              const int* __restrict__ cnt,
                                              const float* __restrict__ as2,
                                              const float* __restrict__ ad2,
                                              const unsigned short* __restrict__ gb,
                                              const float* __restrict__ b2,
                                              float* __restrict__ out){
  __shared__ float wls[8][64];
  __shared__ int   sls[8][64];      // pre-scaled: s*NC (ushort index into gb)
  const int lane = threadIdx.x & 63, w = threadIdx.x >> 6;
  const int n = blockIdx.x * 8 + w;
  int deg = cnt[n]; if (deg > CAP - 1) deg = CAP - 1;   // reserve slot for self
  const int nE = deg + 1;
  const bool act = (lane <= deg);
  int sA = n;                                   // lane==deg -> self loop; lanes>deg -> n
  if (lane < deg) sA = srcp[n * CAP + lane];
  const float ad = ad2[n];
  float v = act ? leaky(as2[sA] + ad) : -3.0e38f;
  sls[w][lane] = sA * NC;
  float mx = v;
#pragma unroll
  for (int o = 1; o < 64; o <<= 1) mx = fmaxf(mx, __shfl_xor(mx, o));
  float wt = act ? __expf(v - mx) : 0.f;
  float den = wt;
#pragma unroll
  for (int o = 1; o < 64; o <<= 1) den += __shfl_xor(den, o);
  wls[w][lane] = wt;                            // 0 for lanes > deg

  // Phase B: lane = class c (lanes 40..63 dup class 39, discarded)
  const int c = min(lane, NC - 1);
  float acc = 0.f;
  {
    float g[16], q[16];
#pragma unroll
    for (int i = 0; i < 16; i++){
      g[i] = bfus(gb[(size_t)(unsigned)(sls[w][i] + c)]);
      q[i] = wls[w][i];                         // 0 beyond nE
    }
#pragma unroll
    for (int i = 0; i < 16; i++) acc += q[i] * g[i];
  }
  for (int i0 = 16; i0 < nE; i0 += 8){          // wave-uniform; j <= 63 always
    float gg[8], qq[8];
#pragma unroll
    for (int t = 0; t < 8; t++){
      const int j = i0 + t;
      gg[t] = bfus(gb[(size_t)(unsigned)(sls[w][j] + c)]);
      qq[t] = wls[w][j];                        // 0 beyond nE
    }
#pragma unroll
    for (int t = 0; t < 8; t++) acc += qq[t] * gg[t];
  }
  const float invd = 1.f / (den + 1e-16f);
  const bool cl = (lane < NC);
  float f = acc * invd + b2[c];
  if (cl) out[(size_t)n * NC + lane] = f;
  float fv = cl ? f : -3.4e38f;
  float m2 = fv;
#pragma unroll
  for (int o = 1; o < 64; o <<= 1) m2 = fmaxf(m2, __shfl_xor(m2, o));
  float ex = cl ? __expf(fv - m2) : 0.f;
#pragma unroll
  for (int o = 1; o < 64; o <<= 1) ex += __shfl_xor(ex, o);
  const float lse = m2 + __logf(ex);
  if (cl) out[(size_t)(NN * NC) + (size_t)n * NC + lane] = fv - lse;
}

extern "C" void kernel_launch(void* const* d_in, const int* in_sizes, int n_in,
                              void* d_out, int out_size, void* d_ws, size_t ws_size,
                              hipStream_t stream){
  const float* x      = (const float*)d_in[0];
  const int*   ei     = (const int*)  d_in[1];
  const float* W1     = (const float*)d_in[3];
  const float* att_s1 = (const float*)d_in[4];
  const float* att_d1 = (const float*)d_in[5];
  const float* b1     = (const float*)d_in[6];
  const float* W2     = (const float*)d_in[7];
  const float* att_s2 = (const float*)d_in[8];
  const float* att_d2 = (const float*)d_in[9];
  const float* b2     = (const float*)d_in[10];
  float* out = (float*)d_out;

  char* wp = (char*)d_ws;
  uint4* W1bfs = (uint4*)wp;                 wp += (size_t)4096 * 16;      // 64 KB
  unsigned short* h1b = (unsigned short*)wp; wp += (size_t)NN * HC * 2;    // 12.8 MB
  unsigned short* h2b = (unsigned short*)wp; wp += (size_t)NN * HC * 2;    // 12.8 MB
  unsigned short* gb  = (unsigned short*)wp; wp += (size_t)NN * NC * 2;    // 4 MB
  float* as1 = (float*)wp;                   wp += (size_t)NN * HD * 4;
  float* ad1 = (float*)wp;                   wp += (size_t)NN * HD * 4;
  float* as2 = (float*)wp;                   wp += (size_t)NN * 4;
  float* ad2 = (float*)wp;                   wp += (size_t)NN * 4;
  int* cnt   = (int*)wp;                     wp += (size_t)NN * 4;
  int* srcp  = (int*)wp;                     wp += (size_t)NN * CAP * 4;   // 12.8 MB

  hipMemsetAsync(cnt, 0, (size_t)NN * sizeof(int), stream);
  k_prep  <<<16, 256, 0, stream>>>(W1, W1bfs);
  k_gemm1 <<<GB1 + SCB, 256, 0, stream>>>(x, W1bfs, att_s1, att_d1, ei, h1b, as1, ad1, cnt, srcp);
  k_agg1  <<<NN / 8, 512, 0, stream>>>(srcp, cnt, as1, ad1, h1b, b1, h2b);
  k_gemm2 <<<(NN + R2 - 1) / R2, 256, 0, stream>>>(h2b, W2, att_s2, att_d2, gb, as2, ad2);
  k_agg2  <<<NN / 8, 512, 0, stream>>>(srcp, cnt, as2, ad2, gb, b2, out);
}

// Round 7
// 238.244 us; speedup vs baseline: 1.3369x; 1.0678x over previous
//
#include <hip/hip_runtime.h>

#define NN 50000
#define EE 800000
#define FIN 256
#define HD 8
#define C1 16
#define HC 128         // HD*C1
#define NC 40
#define NEG 0.2f
#define CAP 64         // ELL capacity per node; P(Poisson(16) >= 64) ~ 1e-17
#define BM 64          // k_gemm1 row tile (4 waves x 16 rows)
#define BM2 64         // k_gemm2 row tile
#define GB1 ((NN + BM - 1) / BM)  // 782 blocks
#define NP_N (NN / 8)  // nodes per partition (6250)
#define SCB 2048       // scatter blocks (8 partitions x 256 ranks), in k_prep dispatch
#define PREPB 19       // 16 W1-swizzle blocks + 3 W2-swizzle blocks

typedef __attribute__((ext_vector_type(8))) short short8;   // 8 bf16 (4 VGPRs)
typedef __attribute__((ext_vector_type(4))) float f32x4;    // MFMA C/D
union FragU { uint4 u; short8 s; };

__device__ __forceinline__ float leaky(float v){ return v > 0.f ? v : NEG * v; }

// fp32 -> bf16 round-to-nearest-even (no NaNs in this workload)
__device__ __forceinline__ unsigned int f2bf(float f){
  unsigned int u = __float_as_uint(f);
  u += 0x7fffu + ((u >> 16) & 1u);
  return u >> 16;
}
__device__ __forceinline__ unsigned int pack2bf(float a, float b){
  return f2bf(a) | (f2bf(b) << 16);
}
__device__ __forceinline__ float bflo(unsigned int u){ return __uint_as_float(u << 16); }
__device__ __forceinline__ float bfhi(unsigned int u){ return __uint_as_float(u & 0xffff0000u); }
__device__ __forceinline__ float bfus(unsigned short u){ return __uint_as_float((unsigned int)u << 16); }

// async 16B global->LDS (DMA, no VGPR round-trip). LDS dest = uniform base + lane*16.
__device__ __forceinline__ void gld_lds16(const void* g, void* l){
  __builtin_amdgcn_global_load_lds((const __attribute__((address_space(1))) unsigned int*)g,
                                   (__attribute__((address_space(3))) unsigned int*)l,
                                   16, 0, 0);
}

// K0 (3 roles by blockIdx):
//  0..15  : W1 (fp32 [256][128]) -> MFMA B-fragments (bf16), as before.
//  16..18 : W2 (fp32 [128][40])  -> MFMA B-fragments, N padded to 48 (3 nt tiles).
//  19..   : XCD-partitioned ELL edge scatter at high occupancy (tiny VGPR state).
__global__ __launch_bounds__(256) void k_prep(const float* __restrict__ W1,
                                              uint4* __restrict__ W1bfs,
                                              const float* __restrict__ W2,
                                              uint4* __restrict__ W2bfs,
                                              const int* __restrict__ ei,
                                              int* __restrict__ cnt,
                                              int* __restrict__ srcp){
  const int tid = threadIdx.x;
  if (blockIdx.x < 16){
    int f = blockIdx.x * 256 + tid;   // 0..4095
    int lane = f & 63, nt = (f >> 6) & 7, kt = f >> 9;
    int quad = lane >> 4, l16 = lane & 15;
    const float* src = W1 + (size_t)(kt * 32 + quad * 8) * HC + nt * 16 + l16;
    unsigned int p[4];
#pragma unroll
    for (int jj = 0; jj < 4; jj++)
      p[jj] = pack2bf(src[(size_t)(2 * jj) * HC], src[(size_t)(2 * jj + 1) * HC]);
    W1bfs[f] = make_uint4(p[0], p[1], p[2], p[3]);
    return;
  }
  if (blockIdx.x < PREPB){
    int f = (blockIdx.x - 16) * 256 + tid;   // 0..767 = 12 fragments x 64 lanes
    int lane = f & 63, frag = f >> 6;        // frag = kt*3 + nt
    int kt = frag / 3, nt = frag - kt * 3;
    int quad = lane >> 4, l16 = lane & 15;
    int n = nt * 16 + l16;                   // output col, pad >= NC with zeros
    int k0 = kt * 32 + quad * 8;
    unsigned int p[4];
#pragma unroll
    for (int jj = 0; jj < 4; jj++){
      float v0 = (n < NC) ? W2[(size_t)(k0 + 2 * jj) * NC + n] : 0.f;
      float v1 = (n < NC) ? W2[(size_t)(k0 + 2 * jj + 1) * NC + n] : 0.f;
      p[jj] = pack2bf(v0, v1);
    }
    W2bfs[f] = make_uint4(p[0], p[1], p[2], p[3]);
    return;
  }
  const int b = blockIdx.x - PREPB;       // 0..SCB-1
  const int part = b & 7, rank = b >> 3;  // each partition gets ranks 0..255
  const int lo = part * NP_N, hi = lo + NP_N;
  for (int e = rank * 256 + tid; e < EE; e += 256 * 256){
    int d = ei[EE + e];
    if (d >= lo && d < hi){
      int s = ei[e];
      int pos = atomicAdd(&cnt[d], 1);
      if (pos < CAP) srcp[d * CAP + pos] = s;   // clamp guard (never hit per Poisson tail)
    }
  }
}

// K1: async-LDS GEMM h1(bf16)[N,128] = x @ W1, bf16 MFMA 16x16x32, BARRIER-FREE.
// Each wave stages its OWN 16 x-rows via 16 global_load_lds (zero VGPR, all async),
// one vmcnt(0), then MFMA from LDS. Source granules pre-swizzled (g ^ (row&7)) so
// the linear DMA write yields 32-bank-spread ds_read_b128 (2 lanes/bank = free).
__global__ __launch_bounds__(256, 2) void k_gemm1(const float* __restrict__ x,
                                                  const uint4* __restrict__ W1bfs,
                                                  const float* __restrict__ att_s,
                                                  const float* __restrict__ att_d,
                                                  unsigned short* __restrict__ h1b,
                                                  float* __restrict__ as1,
                                                  float* __restrict__ ad1){
  __shared__ float xs[BM * FIN];   // 64 KB; wave w owns rows [w*16, w*16+16)
  const int tid = threadIdx.x;
  const int wave = tid >> 6, lane = tid & 63;
  const int quad = lane >> 4, l16 = lane & 15;
  const int m0 = blockIdx.x * BM;
  const int wr0 = wave * 16;

  // stage 16 rows (1 KB each): LDS granule g of local row i holds global granule g^(i&7)
#pragma unroll
  for (int i = 0; i < 16; i++){
    int grow = m0 + wr0 + i; if (grow >= NN) grow = NN - 1;   // clamp (dup stage benign)
    const float* src = x + (size_t)grow * FIN + ((lane ^ (i & 7)) << 2);
    gld_lds16(src, &xs[(wr0 + i) * FIN]);
  }

  FragU bf[8];
#pragma unroll
  for (int nt = 0; nt < 8; nt++) bf[nt].u = W1bfs[nt * 64 + lane];

  asm volatile("s_waitcnt vmcnt(0)" ::: "memory");
  __builtin_amdgcn_sched_barrier(0);

  f32x4 acc[8];
#pragma unroll
  for (int t = 0; t < 8; t++) acc[t] = (f32x4){0.f, 0.f, 0.f, 0.f};

  const int swz = l16 & 7;
  const float* xrow = &xs[(wr0 + l16) * FIN];
#pragma unroll
  for (int kt = 0; kt < 8; kt++){
    FragU bn[8];
    if (kt < 7){
#pragma unroll
      for (int nt = 0; nt < 8; nt++)
        bn[nt].u = W1bfs[((kt + 1) * 8 + nt) * 64 + lane];
    }
    const int g0 = kt * 8 + quad * 2;
    const float4 a0 = *(const float4*)(xrow + ((g0 ^ swz) << 2));
    const float4 a1 = *(const float4*)(xrow + (((g0 + 1) ^ swz) << 2));
    FragU af;
    af.u = make_uint4(pack2bf(a0.x, a0.y), pack2bf(a0.z, a0.w),
                      pack2bf(a1.x, a1.y), pack2bf(a1.z, a1.w));
#pragma unroll
    for (int nt = 0; nt < 8; nt++)
      acc[nt] = __builtin_amdgcn_mfma_f32_16x16x32_bf16(af.s, bf[nt].s, acc[nt], 0, 0, 0);
    if (kt < 7){
#pragma unroll
      for (int nt = 0; nt < 8; nt++) bf[nt] = bn[nt];
    }
  }

  // epilogue: C layout col = lane&15, row = quad*4 + r; head h == nt.
  float sv[8], dv[8];
#pragma unroll
  for (int h = 0; h < 8; h++){ sv[h] = att_s[h * 16 + l16]; dv[h] = att_d[h * 16 + l16]; }
#pragma unroll
  for (int r = 0; r < 4; r++){
    const int gr = m0 + wr0 + quad * 4 + r;
    float s[8], d[8];
#pragma unroll
    for (int h = 0; h < 8; h++){ s[h] = acc[h][r] * sv[h]; d[h] = acc[h][r] * dv[h]; }
#pragma unroll
    for (int o = 1; o < 16; o <<= 1){
#pragma unroll
      for (int h = 0; h < 8; h++){ s[h] += __shfl_xor(s[h], o); d[h] += __shfl_xor(d[h], o); }
    }
    if (gr < NN){
#pragma unroll
      for (int h = 0; h < 8; h++)
        h1b[(size_t)gr * HC + h * 16 + l16] = (unsigned short)f2bf(acc[h][r]);
      if (l16 == 0){
        *(float4*)(as1 + gr * 8)     = make_float4(s[0], s[1], s[2], s[3]);
        *(float4*)(as1 + gr * 8 + 4) = make_float4(s[4], s[5], s[6], s[7]);
        *(float4*)(ad1 + gr * 8)     = make_float4(d[0], d[1], d[2], d[3]);
        *(float4*)(ad1 + gr * 8 + 4) = make_float4(d[4], d[5], d[6], d[7]);
      }
    }
  }
}

// K2: layer-1 aggregate. One wave per node, 8 nodes / 512-thread block, NO barriers.
// Phase A: lane = (head, edge-slot); 3-step butterflies. Phase B: lane = 2 bf16
// channels; static-16 prefetch + 8-wide tail. sls pre-scaled (s<<6 dword row base).
__global__ __launch_bounds__(512) void k_agg1(const int* __restrict__ srcp,
                                              const int* __restrict__ cnt,
                                              const float* __restrict__ as1,
                                              const float* __restrict__ ad1,
                                              const unsigned short* __restrict__ h1b,
                                              const float* __restrict__ b1,
                                              unsigned short* __restrict__ h2b){
  __shared__ float wls[8][64][8];
  __shared__ int   sls[8][64];
  const int lane = threadIdx.x & 63, w = threadIdx.x >> 6;
  const int n = blockIdx.x * 8 + w;
  int deg = cnt[n]; if (deg > CAP - 1) deg = CAP - 1;
  const int nE = deg + 1;
  int sA = n;
  if (lane < deg) sA = srcp[n * CAP + lane];
  sls[w][lane] = sA << 6;

  const int h = lane >> 3, e8 = lane & 7;
  const float adg = ad1[n * 8 + h];
  int nCh = (nE + 7) >> 3; if (nCh < 2) nCh = 2;

  float mx = -3.0e38f;
  for (int c = 0; c < nCh; c++){
    const int i = c * 8 + e8;
    const int s8 = sls[w][i] >> 3;
    const float v = (i < nE) ? leaky(as1[(size_t)(unsigned)(s8 + h)] + adg) : -3.0e38f;
    wls[w][i][h] = v;
    mx = fmaxf(mx, v);
  }
  mx = fmaxf(mx, __shfl_xor(mx, 1));
  mx = fmaxf(mx, __shfl_xor(mx, 2));
  mx = fmaxf(mx, __shfl_xor(mx, 4));

  float den = 0.f;
  for (int c = 0; c < nCh; c++){
    const int i = c * 8 + e8;
    const float v = wls[w][i][h];
    const float wt = (i < nE) ? __expf(v - mx) : 0.f;
    wls[w][i][h] = wt;
    den += wt;
  }
  den += __shfl_xor(den, 1);
  den += __shfl_xor(den, 2);
  den += __shfl_xor(den, 4);

  const unsigned int* hp = (const unsigned int*)h1b;
  float ax = 0.f, ay = 0.f;
  {
    unsigned int u[16]; float q[16];
#pragma unroll
    for (int i = 0; i < 16; i++){
      u[i] = hp[(size_t)(unsigned)(sls[w][i] + lane)];
      q[i] = wls[w][i][h];
    }
#pragma unroll
    for (int i = 0; i < 16; i++){ ax += q[i] * bflo(u[i]); ay += q[i] * bfhi(u[i]); }
  }
  for (int i0 = 16; i0 < nE; i0 += 8){
    unsigned int uu[8]; float qq[8];
#pragma unroll
    for (int t = 0; t < 8; t++){
      const int j = i0 + t;
      uu[t] = hp[(size_t)(unsigned)(sls[w][j] + lane)];
      qq[t] = (j < nE) ? wls[w][j][h] : 0.f;
    }
#pragma unroll
    for (int t = 0; t < 8; t++){ ax += qq[t] * bflo(uu[t]); ay += qq[t] * bfhi(uu[t]); }
  }

  const float invd = 1.f / (den + 1e-16f);
  const float2 bb = *(const float2*)(b1 + 2 * lane);
  float ox = ax * invd + bb.x;
  float oy = ay * invd + bb.y;
  ox = ox > 0.f ? ox : (__expf(ox) - 1.f);
  oy = oy > 0.f ? oy : (__expf(oy) - 1.f);
  *(unsigned int*)(h2b + (size_t)n * HC + 2 * lane) = pack2bf(ox, oy);
}

// K3: MFMA GEMM g(bf16)[N,40] = h2(bf16) @ W2 (N padded to 48, 3 nt tiles), with
// async-LDS staging of h2 rows (source-swizzled) and fused att2 dots. 12 MFMA/wave
// replaces the old ~768 LDS-issues/thread scalar loop. Barrier-free.
__global__ __launch_bounds__(256, 3) void k_gemm2(const unsigned short* __restrict__ h2b,
                                                  const uint4* __restrict__ W2bfs,
                                                  const float* __restrict__ att_s2,
                                                  const float* __restrict__ att_d2,
                                                  unsigned short* __restrict__ gb,
                                                  float* __restrict__ as2,
                                                  float* __restrict__ ad2){
  __shared__ unsigned short h2s[BM2 * HC];   // 16 KB; wave w owns rows [w*16, w*16+16)
  const int tid = threadIdx.x;
  const int wave = tid >> 6, lane = tid & 63;
  const int quad = lane >> 4, l16 = lane & 15;
  const int m0 = blockIdx.x * BM2;
  const int wr0 = wave * 16;

  // stage: 4 issues x 4 rows (256B row = 16 granules); LDS granule g of local row r
  // holds global granule g ^ (r&7).
#pragma unroll
  for (int i = 0; i < 4; i++){
    const int rl = i * 4 + (lane >> 4);   // local row 0..15
    int grow = m0 + wr0 + rl; if (grow >= NN) grow = NN - 1;
    const int g = lane & 15;
    const unsigned short* src = h2b + (size_t)grow * HC + ((g ^ (rl & 7)) << 3);
    gld_lds16(src, &h2s[(wr0 + i * 4) * HC]);
  }

  FragU b2f[12];
#pragma unroll
  for (int f = 0; f < 12; f++) b2f[f].u = W2bfs[f * 64 + lane];

  asm volatile("s_waitcnt vmcnt(0)" ::: "memory");
  __builtin_amdgcn_sched_barrier(0);

  f32x4 acc[3];
#pragma unroll
  for (int t = 0; t < 3; t++) acc[t] = (f32x4){0.f, 0.f, 0.f, 0.f};

  const int swz = l16 & 7;
  const unsigned short* hrow = &h2s[(wr0 + l16) * HC];
#pragma unroll
  for (int kt = 0; kt < 4; kt++){
    FragU af;
    af.u = *(const uint4*)(hrow + (((kt * 4 + quad) ^ swz) << 3));
#pragma unroll
    for (int nt = 0; nt < 3; nt++)
      acc[nt] = __builtin_amdgcn_mfma_f32_16x16x32_bf16(af.s, b2f[kt * 3 + nt].s, acc[nt], 0, 0, 0);
  }

  // epilogue: col c = nt*16 + l16 (valid c < 40), row = quad*4 + r.
  float sv[3], dv[3];
#pragma unroll
  for (int nt = 0; nt < 3; nt++){
    const int c = nt * 16 + l16;
    sv[nt] = (c < NC) ? att_s2[c] : 0.f;
    dv[nt] = (c < NC) ? att_d2[c] : 0.f;
  }
#pragma unroll
  for (int r = 0; r < 4; r++){
    const int gr = m0 + wr0 + quad * 4 + r;
    float s = acc[0][r] * sv[0] + acc[1][r] * sv[1] + acc[2][r] * sv[2];
    float d = acc[0][r] * dv[0] + acc[1][r] * dv[1] + acc[2][r] * dv[2];
#pragma unroll
    for (int o = 1; o < 16; o <<= 1){ s += __shfl_xor(s, o); d += __shfl_xor(d, o); }
    if (gr < NN){
#pragma unroll
      for (int nt = 0; nt < 3; nt++){
        const int c = nt * 16 + l16;
        if (c < NC) gb[(size_t)gr * NC + c] = (unsigned short)f2bf(acc[nt][r]);
      }
      if (l16 == 0){ as2[gr] = s; ad2[gr] = d; }
    }
  }
}

// K4: layer-2 aggregate, two-phase lane-parallel softmax + log_softmax. One wave
// per node, 8 nodes / 512-thread block, NO barriers. sls pre-scaled (s*NC).
__global__ __launch_bounds__(512) void k_agg2(const int* __restrict__ srcp,
                                              const int* __restrict__ cnt,
                                              const float* __restrict__ as2,
                                              const float* __restrict__ ad2,
                                              const unsigned short* __restrict__ gb,
                                              const float* __restrict__ b2,
                                              float* __restrict__ out){
  __shared__ float wls[8][64];
  __shared__ int   sls[8][64];
  const int lane = threadIdx.x & 63, w = threadIdx.x >> 6;
  const int n = blockIdx.x * 8 + w;
  int deg = cnt[n]; if (deg > CAP - 1) deg = CAP - 1;
  const int nE = deg + 1;
  const bool act = (lane <= deg);
  int sA = n;
  if (lane < deg) sA = srcp[n * CAP + lane];
  const float ad = ad2[n];
  float v = act ? leaky(as2[sA] + ad) : -3.0e38f;
  sls[w][lane] = sA * NC;
  float mx = v;
#pragma unroll
  for (int o = 1; o < 64; o <<= 1) mx = fmaxf(mx, __shfl_xor(mx, o));
  float wt = act ? __expf(v - mx) : 0.f;
  float den = wt;
#pragma unroll
  for (int o = 1; o < 64; o <<= 1) den += __shfl_xor(den, o);
  wls[w][lane] = wt;

  const int c = min(lane, NC - 1);
  float acc = 0.f;
  {
    float g[16], q[16];
#pragma unroll
    for (int i = 0; i < 16; i++){
      g[i] = bfus(gb[(size_t)(unsigned)(sls[w][i] + c)]);
      q[i] = wls[w][i];
    }
#pragma unroll
    for (int i = 0; i < 16; i++) acc += q[i] * g[i];
  }
  for (int i0 = 16; i0 < nE; i0 += 8){
    float gg[8], qq[8];
#pragma unroll
    for (int t = 0; t < 8; t++){
      const int j = i0 + t;
      gg[t] = bfus(gb[(size_t)(unsigned)(sls[w][j] + c)]);
      qq[t] = wls[w][j];
    }
#pragma unroll
    for (int t = 0; t < 8; t++) acc += qq[t] * gg[t];
  }
  const float invd = 1.f / (den + 1e-16f);
  const bool cl = (lane < NC);
  float f = acc * invd + b2[c];
  if (cl) out[(size_t)n * NC + lane] = f;
  float fv = cl ? f : -3.4e38f;
  float m2 = fv;
#pragma unroll
  for (int o = 1; o < 64; o <<= 1) m2 = fmaxf(m2, __shfl_xor(m2, o));
  float ex = cl ? __expf(fv - m2) : 0.f;
#pragma unroll
  for (int o = 1; o < 64; o <<= 1) ex += __shfl_xor(ex, o);
  const float lse = m2 + __logf(ex);
  if (cl) out[(size_t)(NN * NC) + (size_t)n * NC + lane] = fv - lse;
}

extern "C" void kernel_launch(void* const* d_in, const int* in_sizes, int n_in,
                              void* d_out, int out_size, void* d_ws, size_t ws_size,
                              hipStream_t stream){
  const float* x      = (const float*)d_in[0];
  const int*   ei     = (const int*)  d_in[1];
  const float* W1     = (const float*)d_in[3];
  const float* att_s1 = (const float*)d_in[4];
  const float* att_d1 = (const float*)d_in[5];
  const float* b1     = (const float*)d_in[6];
  const float* W2     = (const float*)d_in[7];
  const float* att_s2 = (const float*)d_in[8];
  const float* att_d2 = (const float*)d_in[9];
  const float* b2     = (const float*)d_in[10];
  float* out = (float*)d_out;

  char* wp = (char*)d_ws;
  uint4* W1bfs = (uint4*)wp;                 wp += (size_t)4096 * 16;      // 64 KB
  uint4* W2bfs = (uint4*)wp;                 wp += (size_t)768 * 16;       // 12 KB
  unsigned short* h1b = (unsigned short*)wp; wp += (size_t)NN * HC * 2;    // 12.8 MB
  unsigned short* h2b = (unsigned short*)wp; wp += (size_t)NN * HC * 2;    // 12.8 MB
  unsigned short* gb  = (unsigned short*)wp; wp += (size_t)NN * NC * 2;    // 4 MB
  float* as1 = (float*)wp;                   wp += (size_t)NN * HD * 4;
  float* ad1 = (float*)wp;                   wp += (size_t)NN * HD * 4;
  float* as2 = (float*)wp;                   wp += (size_t)NN * 4;
  float* ad2 = (float*)wp;                   wp += (size_t)NN * 4;
  int* cnt   = (int*)wp;                     wp += (size_t)NN * 4;
  int* srcp  = (int*)wp;                     wp += (size_t)NN * CAP * 4;   // 12.8 MB

  hipMemsetAsync(cnt, 0, (size_t)NN * sizeof(int), stream);
  k_prep  <<<PREPB + SCB, 256, 0, stream>>>(W1, W1bfs, W2, W2bfs, ei, cnt, srcp);
  k_gemm1 <<<GB1, 256, 0, stream>>>(x, W1bfs, att_s1, att_d1, h1b, as1, ad1);
  k_agg1  <<<NN / 8, 512, 0, stream>>>(srcp, cnt, as1, ad1, h1b, b1, h2b);
  k_gemm2 <<<(NN + BM2 - 1) / BM2, 256, 0, stream>>>(h2b, W2bfs, att_s2, att_d2, gb, as2, ad2);
  k_agg2  <<<NN / 8, 512, 0, stream>>>(srcp, cnt, as2, ad2, gb, b2, out);
}